// Round 2
// baseline (294.901 us; speedup 1.0000x reference)
//
#include <hip/hip_runtime.h>
#include <string.h>

#define ALPHA 0.2f
// B=128, L=512, FIN=FOUT=128. Global I/O fp32; internal GEMMs bf16 MFMA.

typedef short short8 __attribute__((ext_vector_type(8)));
typedef float floatx4 __attribute__((ext_vector_type(4)));
typedef int intx4 __attribute__((ext_vector_type(4)));
typedef unsigned short ushort4v __attribute__((ext_vector_type(4)));

__device__ inline unsigned short f2bf(float f) {
    unsigned int v; __builtin_memcpy(&v, &f, 4);
    v = v + 0x7FFFu + ((v >> 16) & 1u);   // RNE
    return (unsigned short)(v >> 16);
}

__device__ inline floatx4 ntload_f4(const float* p) {
    return __builtin_nontemporal_load((const floatx4*)p);
}

// ---------------------------------------------------------------------------
// Kernel 1: Wh^T = (h @ W)^T via swapped MFMA operands (A=W^T rows=o, B=h rows=j)
// C/D tile natively [o][j]. Emits ei/ej from fp32 accumulators.
// 512 threads/block (8 waves), grid 512. LDS 70.7KB -> 2 blk/CU = 16 waves/CU.
// ---------------------------------------------------------------------------
__global__ __launch_bounds__(512, 4) void wh_kernel(const float* __restrict__ h,
                                                    const float* __restrict__ W,
                                                    const float* __restrict__ a,
                                                    unsigned short* __restrict__ wht,
                                                    float* __restrict__ ei,
                                                    float* __restrict__ ej)
{
    __shared__ __align__(16) unsigned short h_s[128][136];  // [j_local][f] bf16
    __shared__ __align__(16) unsigned short w_s[128][136];  // [o][f] bf16
    __shared__ float a_s[256];
    const int tid  = threadIdx.x;
    const int lane = tid & 63;
    const int wv   = tid >> 6;        // 0..7
    const int quad = lane >> 4;
    const int l16  = lane & 15;
    const int r0   = blockIdx.x * 128;
    const int b    = r0 >> 9;
    const int jb   = r0 & 511;

    const float* hbase = h + (size_t)r0 * 128;
#pragma unroll
    for (int it = 0; it < 8; ++it) {
        int idx4 = it * 512 + tid;               // 4096 float4 chunks
        floatx4 v = ntload_f4(hbase + idx4 * 4); // h read exactly once -> nt
        int row = idx4 >> 5;
        int col = (idx4 & 31) * 4;
        ushort4v u;
        for (int e = 0; e < 4; ++e) u[e] = f2bf(v[e]);
        *(ushort4v*)&h_s[row][col] = u;
    }
#pragma unroll
    for (int it = 0; it < 32; ++it) {
        int idx = it * 512 + tid;
        w_s[idx & 127][idx >> 7] = f2bf(W[idx]);
    }
    if (tid < 256) a_s[tid] = a[tid];
    __syncthreads();

    floatx4 acc[8];
#pragma unroll
    for (int mo = 0; mo < 8; ++mo) acc[mo] = (floatx4)0.f;

#pragma unroll
    for (int kk = 0; kk < 4; ++kk) {
        short8 bfr = *(const short8*)&h_s[wv * 16 + l16][kk * 32 + quad * 8];
#pragma unroll
        for (int mo = 0; mo < 8; ++mo) {
            short8 afr = *(const short8*)&w_s[mo * 16 + l16][kk * 32 + quad * 8];
            acc[mo] = __builtin_amdgcn_mfma_f32_16x16x32_bf16(afr, bfr, acc[mo], 0, 0, 0);
        }
    }

    // ei/ej from fp32 accumulators (dot with a[:128] / a[128:])
    {
        float si = 0.f, sj = 0.f;
#pragma unroll
        for (int mo = 0; mo < 8; ++mo)
            for (int r = 0; r < 4; ++r) {
                int o = mo * 16 + quad * 4 + r;
                float v = acc[mo][r];
                si += v * a_s[o];
                sj += v * a_s[128 + o];
            }
        si += __shfl_xor(si, 16); si += __shfl_xor(si, 32);
        sj += __shfl_xor(sj, 16); sj += __shfl_xor(sj, 32);
        if (quad == 0) {
            int j = jb + wv * 16 + l16;
            ei[b * 512 + j] = si;
            ej[b * 512 + j] = sj;
        }
    }

#pragma unroll
    for (int mo = 0; mo < 8; ++mo)
        for (int r = 0; r < 4; ++r) {
            int o = mo * 16 + quad * 4 + r;
            int j = jb + wv * 16 + l16;
            wht[(size_t)b * 65536 + o * 512 + j] = f2bf(acc[mo][r]);
        }
}

// ---------------------------------------------------------------------------
// Kernel 2 (fused, barrier-free main loop): per wave, 16 output rows.
// Loop over 16 j-tiles of 32: load bias/adj frag (prefetch d=1), compute
// P directly in MFMA A-frag layout (lane(q,l16) owns p[i=l16][j=jt*32+q*8+e]),
// 8 MFMAs with B-frags streamed per-wave from L2-resident wht.
// No p_s LDS, no barriers in the loop -> memory and MFMA pipes stay co-active.
// grid 1024 x 256 (4 waves/block, 64 rows/block). LDS ~2.3KB.
// ---------------------------------------------------------------------------
__global__ __launch_bounds__(256, 4) void attn_fused(const unsigned short* __restrict__ wht,
                                                     const float* __restrict__ ei,
                                                     const float* __restrict__ ej,
                                                     const float* __restrict__ bias,
                                                     const int* __restrict__ adj,
                                                     float* __restrict__ out)
{
    __shared__ __align__(16) float ej_s[512];
    __shared__ float s_row_s[64];

    const int tid  = threadIdx.x;
    const int lane = tid & 63;
    const int wv   = tid >> 6;        // 0..3
    const int quad = lane >> 4;
    const int l16  = lane & 15;
    const int b    = blockIdx.x >> 3;
    const int i0   = (blockIdx.x & 7) * 64;
    const int iw   = i0 + wv * 16;    // this wave's first output row

    // Per-lane stream bases (row = iw + l16, col window starts at quad*8)
    const float* bp = bias + ((size_t)(b * 512 + iw + l16)) * 512 + quad * 8;
    const int*   ap = adj + (iw + l16) * 512 + quad * 8;
    const unsigned short* wbase = wht + (size_t)b * 65536 + l16 * 512 + quad * 8;

    // Issue first-tile loads before anything else (latency hiding).
    floatx4 cb0 = ntload_f4(bp);                 // bias streamed once -> nt
    floatx4 cb1 = ntload_f4(bp + 4);
    intx4   cm0 = *(const intx4*)(ap);           // adj reused across b -> cached
    intx4   cm1 = *(const intx4*)(ap + 4);
    const float eiv = ei[b * 512 + iw + l16];

    // Stage ej row (2KB) for broadcast reads.
    if (tid < 128) *(floatx4*)&ej_s[tid * 4] = *(const floatx4*)(ej + b * 512 + tid * 4);
    __syncthreads();

    floatx4 acc[8];
#pragma unroll
    for (int mo = 0; mo < 8; ++mo) acc[mo] = (floatx4)0.f;

    float rsum = 0.f;

#pragma unroll
    for (int jt = 0; jt < 16; ++jt) {
        // B-frag group A (o = 0..63 slice for this lane) — issue early
        short8 wfa[4];
#pragma unroll
        for (int mo = 0; mo < 4; ++mo)
            wfa[mo] = *(const short8*)(wbase + mo * 16 * 512 + jt * 32);

        // Prefetch next tile's bias/adj while computing this one
        floatx4 nb0, nb1; intx4 nm0, nm1;
        if (jt < 15) {
            nb0 = ntload_f4(bp + (jt + 1) * 32);
            nb1 = ntload_f4(bp + (jt + 1) * 32 + 4);
            nm0 = *(const intx4*)(ap + (jt + 1) * 32);
            nm1 = *(const intx4*)(ap + (jt + 1) * 32 + 4);
        }

        // ej broadcast (uniform address per quad -> conflict-free)
        floatx4 ejv0 = *(const floatx4*)&ej_s[jt * 32 + quad * 8];
        floatx4 ejv1 = *(const floatx4*)&ej_s[jt * 32 + quad * 8 + 4];

        // P fragment in A-frag layout: af[k] = p[i=l16][j = jt*32 + quad*8 + k]
        short8 af;
        float sm = 0.f;
#pragma unroll
        for (int e = 0; e < 4; ++e) {
            float x = eiv + ejv0[e];
            x = fmaxf(x, ALPHA * x);             // leaky relu
            x += cb0[e];
            float p = __expf(x);                 // no max-subtraction (|x| small)
            p = (cm0[e] != 0) ? p : 0.f;
            sm += p;
            af[e] = (short)f2bf(p);
        }
#pragma unroll
        for (int e = 0; e < 4; ++e) {
            float x = eiv + ejv1[e];
            x = fmaxf(x, ALPHA * x);
            x += cb1[e];
            float p = __expf(x);
            p = (cm1[e] != 0) ? p : 0.f;
            sm += p;
            af[4 + e] = (short)f2bf(p);
        }
        rsum += sm;

        // B-frag group B (o = 64..127 slice)
        short8 wfb[4];
#pragma unroll
        for (int mo = 0; mo < 4; ++mo)
            wfb[mo] = *(const short8*)(wbase + (mo + 4) * 16 * 512 + jt * 32);

#pragma unroll
        for (int mo = 0; mo < 4; ++mo)
            acc[mo] = __builtin_amdgcn_mfma_f32_16x16x32_bf16(af, wfa[mo], acc[mo], 0, 0, 0);
#pragma unroll
        for (int mo = 0; mo < 4; ++mo)
            acc[mo + 4] = __builtin_amdgcn_mfma_f32_16x16x32_bf16(af, wfb[mo], acc[mo + 4], 0, 0, 0);

        cb0 = nb0; cb1 = nb1; cm0 = nm0; cm1 = nm1;
    }

    // Row sums: lane holds partial for row l16 over its 8 cols; reduce across quads.
    rsum += __shfl_xor(rsum, 16);
    rsum += __shfl_xor(rsum, 32);
    if (lane < 16) s_row_s[wv * 16 + lane] = rsum;   // quad==0 lanes: row l16
    __syncthreads();

    // Epilogue: normalize (acc row = quad*4+r), elu, store.
    float inv[4];
#pragma unroll
    for (int r = 0; r < 4; ++r) inv[r] = 1.0f / s_row_s[wv * 16 + quad * 4 + r];

#pragma unroll
    for (int mo = 0; mo < 8; ++mo)
#pragma unroll
        for (int r = 0; r < 4; ++r) {
            int i = iw + quad * 4 + r;
            float v = acc[mo][r] * inv[r];
            v = v > 0.f ? v : (__expf(v) - 1.f);
            out[((size_t)(b * 512 + i)) * 128 + mo * 16 + l16] = v;
        }
}

// ---------------------------------------------------------------------------
extern "C" void kernel_launch(void* const* d_in, const int* in_sizes, int n_in,
                              void* d_out, int out_size, void* d_ws, size_t ws_size,
                              hipStream_t stream)
{
    const float* h    = (const float*)d_in[0];
    const float* W    = (const float*)d_in[1];
    const float* a    = (const float*)d_in[2];
    const float* bias = (const float*)d_in[3];
    const int*   adj  = (const int*)d_in[4];
    float*       out  = (float*)d_out;

    unsigned short* wht = (unsigned short*)d_ws;          // 16.78 MB bf16 Wh_t[b][o][j]
    float* ei = (float*)((char*)d_ws + 16777216);
    float* ej = ei + 65536;

    hipLaunchKernelGGL(wh_kernel,   dim3(512),  dim3(512), 0, stream, h, W, a, wht, ei, ej);
    hipLaunchKernelGGL(attn_fused,  dim3(1024), dim3(256), 0, stream, wht, ei, ej, bias, adj, out);
}

// Round 4
// 278.530 us; speedup vs baseline: 1.0588x; 1.0588x over previous
//
#include <hip/hip_runtime.h>
#include <string.h>

#define ALPHA 0.2f
// B=128, L=512, FIN=FOUT=128. Global I/O fp32; internal GEMMs bf16 MFMA.

typedef short short8 __attribute__((ext_vector_type(8)));
typedef float floatx4 __attribute__((ext_vector_type(4)));
typedef int intx4 __attribute__((ext_vector_type(4)));
typedef unsigned short ushort4v __attribute__((ext_vector_type(4)));

__device__ inline unsigned short f2bf(float f) {
    unsigned int v; __builtin_memcpy(&v, &f, 4);
    v = v + 0x7FFFu + ((v >> 16) & 1u);   // RNE
    return (unsigned short)(v >> 16);
}

__device__ inline floatx4 ntload_f4(const float* p) {
    return __builtin_nontemporal_load((const floatx4*)p);
}

// ---------------------------------------------------------------------------
// Kernel 1 (round-0 proven ~20us): Wh^T = (h @ W)^T via swapped MFMA operands.
// grid 512 x 256 threads.
// ---------------------------------------------------------------------------
__global__ __launch_bounds__(256) void wh_kernel(const float* __restrict__ h,
                                                 const float* __restrict__ W,
                                                 const float* __restrict__ a,
                                                 unsigned short* __restrict__ wht,
                                                 float* __restrict__ ei,
                                                 float* __restrict__ ej)
{
    __shared__ __align__(16) unsigned short h_s[128][136];  // [j_local][f] bf16
    __shared__ __align__(16) unsigned short w_s[128][136];  // [o][f] bf16
    __shared__ float a_s[256];
    const int tid  = threadIdx.x;
    const int lane = tid & 63;
    const int wv   = tid >> 6;
    const int quad = lane >> 4;
    const int l16  = lane & 15;
    const int r0   = blockIdx.x * 128;
    const int b    = r0 >> 9;
    const int jb   = r0 & 511;

    const float* hbase = h + (size_t)r0 * 128;
    for (int it = 0; it < 16; ++it) {
        int idx4 = it * 256 + tid;
        floatx4 v = *(const floatx4*)(hbase + idx4 * 4);
        int row = idx4 >> 5;
        int col = (idx4 & 31) * 4;
        ushort4v u;
        for (int e = 0; e < 4; ++e) u[e] = f2bf(v[e]);
        *(ushort4v*)&h_s[row][col] = u;
    }
    for (int it = 0; it < 64; ++it) {
        int idx = it * 256 + tid;
        w_s[idx & 127][idx >> 7] = f2bf(W[idx]);
    }
    a_s[tid] = a[tid];
    __syncthreads();

    floatx4 acc[8][2];
    for (int mo = 0; mo < 8; ++mo)
        for (int n = 0; n < 2; ++n) acc[mo][n] = (floatx4)0.f;

    for (int kk = 0; kk < 4; ++kk) {
        short8 bfr[2];
        for (int n = 0; n < 2; ++n)
            bfr[n] = *(const short8*)&h_s[wv * 32 + n * 16 + l16][kk * 32 + quad * 8];
        for (int mo = 0; mo < 8; ++mo) {
            short8 afr = *(const short8*)&w_s[mo * 16 + l16][kk * 32 + quad * 8];
            acc[mo][0] = __builtin_amdgcn_mfma_f32_16x16x32_bf16(afr, bfr[0], acc[mo][0], 0, 0, 0);
            acc[mo][1] = __builtin_amdgcn_mfma_f32_16x16x32_bf16(afr, bfr[1], acc[mo][1], 0, 0, 0);
        }
    }

    for (int n = 0; n < 2; ++n) {
        float si = 0.f, sj = 0.f;
        for (int mo = 0; mo < 8; ++mo)
            for (int r = 0; r < 4; ++r) {
                int o = mo * 16 + quad * 4 + r;
                float v = acc[mo][n][r];
                si += v * a_s[o];
                sj += v * a_s[128 + o];
            }
        si += __shfl_xor(si, 16); si += __shfl_xor(si, 32);
        sj += __shfl_xor(sj, 16); sj += __shfl_xor(sj, 32);
        if (quad == 0) {
            int j = jb + wv * 32 + n * 16 + l16;
            ei[b * 512 + j] = si;
            ej[b * 512 + j] = sj;
        }
    }

    for (int mo = 0; mo < 8; ++mo)
        for (int n = 0; n < 2; ++n)
            for (int r = 0; r < 4; ++r) {
                int o = mo * 16 + quad * 4 + r;
                int j = jb + wv * 32 + n * 16 + l16;
                wht[(size_t)b * 65536 + o * 512 + j] = f2bf(acc[mo][n][r]);
            }
}

// ---------------------------------------------------------------------------
// Kernel 2: pure-streaming score kernel. One wave per (b,i) row.
// Reads bias (nt, streamed once), adj (L2-reused across b), ej (L2), ei.
// Writes P row (bf16, coalesced 1KB/wave) + fp32 row-sum.
// No LDS, no barriers, small VGPR -> max occupancy streaming regime.
// grid 16384 x 256 (4 rows/block).
// ---------------------------------------------------------------------------
__global__ __launch_bounds__(256) void score_kernel(const float* __restrict__ ei,
                                                    const float* __restrict__ ej,
                                                    const float* __restrict__ bias,
                                                    const int* __restrict__ adj,
                                                    unsigned short* __restrict__ p,
                                                    float* __restrict__ srow)
{
    const int tid  = threadIdx.x;
    const int lane = tid & 63;
    const int wv   = tid >> 6;
    const int row  = blockIdx.x * 4 + wv;     // b*512 + i
    const int i    = row & 511;
    const int b    = row >> 9;

    const float* bp  = bias + (size_t)row * 512 + lane * 8;
    const int*   ap  = adj + i * 512 + lane * 8;
    const float* ejp = ej + b * 512 + lane * 8;

    // Issue all loads upfront (6 x 16B per lane in flight).
    floatx4 b0 = ntload_f4(bp);
    floatx4 b1 = ntload_f4(bp + 4);
    intx4   m0 = *(const intx4*)(ap);
    intx4   m1 = *(const intx4*)(ap + 4);
    floatx4 e0 = *(const floatx4*)(ejp);
    floatx4 e1 = *(const floatx4*)(ejp + 4);
    const float eiv = ei[row];

    short8 pv;
    float sm = 0.f;
#pragma unroll
    for (int e = 0; e < 4; ++e) {
        float x = eiv + e0[e];
        x = fmaxf(x, ALPHA * x);               // leaky relu
        x += b0[e];
        float pe = __expf(x);                  // no max-subtraction (|x| small)
        pe = (m0[e] != 0) ? pe : 0.f;
        sm += pe;
        pv[e] = (short)f2bf(pe);
    }
#pragma unroll
    for (int e = 0; e < 4; ++e) {
        float x = eiv + e1[e];
        x = fmaxf(x, ALPHA * x);
        x += b1[e];
        float pe = __expf(x);
        pe = (m1[e] != 0) ? pe : 0.f;
        sm += pe;
        pv[4 + e] = (short)f2bf(pe);
    }

#pragma unroll
    for (int off = 32; off; off >>= 1) sm += __shfl_xor(sm, off);

    *(short8*)(p + (size_t)row * 512 + lane * 8) = pv;   // coalesced, L3-allocating
    if (lane == 0) srow[row] = sm;
}

// ---------------------------------------------------------------------------
// Kernel 3: C[32x128] = P[32x512] @ Wh[512x128] per (b, i-tile) block.
// P tile staged global->LDS (coalesced 16B/thread); Phase B verbatim from the
// round-1 kernel that passed. grid 2048 x 512 (8 waves, o-slice 16 each).
// LDS ~33.4KB -> 4 blk/CU = 32 waves/CU.
// ---------------------------------------------------------------------------
__global__ __launch_bounds__(512, 8) void pv_kernel(const unsigned short* __restrict__ p,
                                                    const float* __restrict__ srow,
                                                    const unsigned short* __restrict__ wht,
                                                    float* __restrict__ out)
{
    __shared__ __align__(16) unsigned short p_s[32][520];
    __shared__ float s_row_s[32];

    const int tid  = threadIdx.x;
    const int lane = tid & 63;
    const int wv   = tid >> 6;        // 0..7
    const int quad = lane >> 4;
    const int l16  = lane & 15;
    const int b    = blockIdx.x >> 4;
    const int i0   = (blockIdx.x & 15) * 32;

    // Prime Phase-B B-frag stream early (L2-resident wht).
    const unsigned short* wb = wht + (size_t)b * 65536 + (wv * 16 + l16) * 512 + quad * 8;
    short8 bf = *(const short8*)(wb);

    // Stage P tile [32][512] bf16 = 32KB, coalesced 16B/thread, 4 iters.
    const unsigned short* psrc = p + ((size_t)(b * 512 + i0)) * 512;
#pragma unroll
    for (int it = 0; it < 4; ++it) {
        int idx = it * 512 + tid;
        short8 v = *(const short8*)(psrc + idx * 8);
        *(short8*)&p_s[idx >> 6][(idx & 63) * 8] = v;
    }
    if (tid < 32) s_row_s[tid] = srow[b * 512 + i0 + tid];
    __syncthreads();

    floatx4 acc[2];
    acc[0] = (floatx4)0.f;
    acc[1] = (floatx4)0.f;

#pragma unroll
    for (int k16 = 0; k16 < 16; ++k16) {
        int ko = k16 * 32 + quad * 8;
        short8 nbf;
        if (k16 < 15) nbf = *(const short8*)(wb + (k16 + 1) * 32);
        short8 af0 = *(const short8*)&p_s[l16][ko];
        short8 af1 = *(const short8*)&p_s[16 + l16][ko];
        acc[0] = __builtin_amdgcn_mfma_f32_16x16x32_bf16(af0, bf, acc[0], 0, 0, 0);
        acc[1] = __builtin_amdgcn_mfma_f32_16x16x32_bf16(af1, bf, acc[1], 0, 0, 0);
        bf = nbf;
    }

    // Epilogue: normalize, elu, fp32 nontemporal store.
#pragma unroll
    for (int m = 0; m < 2; ++m)
#pragma unroll
        for (int r = 0; r < 4; ++r) {
            int il = m * 16 + quad * 4 + r;
            int o  = wv * 16 + l16;
            float v = acc[m][r] / s_row_s[il];
            v = v > 0.f ? v : (__expf(v) - 1.f);
            __builtin_nontemporal_store(v, &out[((size_t)(b * 512 + i0 + il)) * 128 + o]);
        }
}

// ---------------------------------------------------------------------------
extern "C" void kernel_launch(void* const* d_in, const int* in_sizes, int n_in,
                              void* d_out, int out_size, void* d_ws, size_t ws_size,
                              hipStream_t stream)
{
    const float* h    = (const float*)d_in[0];
    const float* W    = (const float*)d_in[1];
    const float* a    = (const float*)d_in[2];
    const float* bias = (const float*)d_in[3];
    const int*   adj  = (const int*)d_in[4];
    float*       out  = (float*)d_out;

    unsigned short* wht = (unsigned short*)d_ws;                      // 16.78 MB
    float* ei = (float*)((char*)d_ws + 16777216);                     // 256 KB
    float* ej = ei + 65536;                                           // 256 KB
    unsigned short* pbuf = (unsigned short*)((char*)d_ws + 17301504); // 67.1 MB
    float* srow = (float*)((char*)d_ws + 17301504 + 67108864);        // 256 KB

    hipLaunchKernelGGL(wh_kernel,    dim3(512),   dim3(256), 0, stream, h, W, a, wht, ei, ej);
    hipLaunchKernelGGL(score_kernel, dim3(16384), dim3(256), 0, stream, ei, ej, bias, adj, pbuf, srow);
    hipLaunchKernelGGL(pv_kernel,    dim3(2048),  dim3(512), 0, stream, pbuf, srow, wht, out);
}

// Round 5
// 262.191 us; speedup vs baseline: 1.1248x; 1.0623x over previous
//
#include <hip/hip_runtime.h>
#include <string.h>

#define ALPHA 0.2f
// B=128, L=512, FIN=FOUT=128. Global I/O fp32; internal GEMMs bf16 MFMA.

typedef short short8 __attribute__((ext_vector_type(8)));
typedef float floatx4 __attribute__((ext_vector_type(4)));
typedef int intx4 __attribute__((ext_vector_type(4)));
typedef unsigned short ushort4v __attribute__((ext_vector_type(4)));

__device__ inline unsigned short f2bf(float f) {
    unsigned int v; __builtin_memcpy(&v, &f, 4);
    v = v + 0x7FFFu + ((v >> 16) & 1u);   // RNE
    return (unsigned short)(v >> 16);
}

// ---------------------------------------------------------------------------
// Kernel 1 (round-0 proven ~20us): Wh^T = (h @ W)^T via swapped MFMA operands.
// grid 512 x 256 threads.
// ---------------------------------------------------------------------------
__global__ __launch_bounds__(256) void wh_kernel(const float* __restrict__ h,
                                                 const float* __restrict__ W,
                                                 const float* __restrict__ a,
                                                 unsigned short* __restrict__ wht,
                                                 float* __restrict__ ei,
                                                 float* __restrict__ ej)
{
    __shared__ __align__(16) unsigned short h_s[128][136];  // [j_local][f] bf16
    __shared__ __align__(16) unsigned short w_s[128][136];  // [o][f] bf16
    __shared__ float a_s[256];
    const int tid  = threadIdx.x;
    const int lane = tid & 63;
    const int wv   = tid >> 6;
    const int quad = lane >> 4;
    const int l16  = lane & 15;
    const int r0   = blockIdx.x * 128;
    const int b    = r0 >> 9;
    const int jb   = r0 & 511;

    const float* hbase = h + (size_t)r0 * 128;
    for (int it = 0; it < 16; ++it) {
        int idx4 = it * 256 + tid;
        floatx4 v = *(const floatx4*)(hbase + idx4 * 4);
        int row = idx4 >> 5;
        int col = (idx4 & 31) * 4;
        ushort4v u;
        for (int e = 0; e < 4; ++e) u[e] = f2bf(v[e]);
        *(ushort4v*)&h_s[row][col] = u;
    }
    for (int it = 0; it < 64; ++it) {
        int idx = it * 256 + tid;
        w_s[idx & 127][idx >> 7] = f2bf(W[idx]);
    }
    a_s[tid] = a[tid];
    __syncthreads();

    floatx4 acc[8][2];
    for (int mo = 0; mo < 8; ++mo)
        for (int n = 0; n < 2; ++n) acc[mo][n] = (floatx4)0.f;

    for (int kk = 0; kk < 4; ++kk) {
        short8 bfr[2];
        for (int n = 0; n < 2; ++n)
            bfr[n] = *(const short8*)&h_s[wv * 32 + n * 16 + l16][kk * 32 + quad * 8];
        for (int mo = 0; mo < 8; ++mo) {
            short8 afr = *(const short8*)&w_s[mo * 16 + l16][kk * 32 + quad * 8];
            acc[mo][0] = __builtin_amdgcn_mfma_f32_16x16x32_bf16(afr, bfr[0], acc[mo][0], 0, 0, 0);
            acc[mo][1] = __builtin_amdgcn_mfma_f32_16x16x32_bf16(afr, bfr[1], acc[mo][1], 0, 0, 0);
        }
    }

    for (int n = 0; n < 2; ++n) {
        float si = 0.f, sj = 0.f;
        for (int mo = 0; mo < 8; ++mo)
            for (int r = 0; r < 4; ++r) {
                int o = mo * 16 + quad * 4 + r;
                float v = acc[mo][n][r];
                si += v * a_s[o];
                sj += v * a_s[128 + o];
            }
        si += __shfl_xor(si, 16); si += __shfl_xor(si, 32);
        sj += __shfl_xor(sj, 16); sj += __shfl_xor(sj, 32);
        if (quad == 0) {
            int j = jb + wv * 32 + n * 16 + l16;
            ei[b * 512 + j] = si;
            ej[b * 512 + j] = sj;
        }
    }

    for (int mo = 0; mo < 8; ++mo)
        for (int n = 0; n < 2; ++n)
            for (int r = 0; r < 4; ++r) {
                int o = mo * 16 + quad * 4 + r;
                int j = jb + wv * 32 + n * 16 + l16;
                wht[(size_t)b * 65536 + o * 512 + j] = f2bf(acc[mo][n][r]);
            }
}

// ---------------------------------------------------------------------------
// Kernel 2: scores -> softmax -> att @ Wh -> elu. R0 structure (one block per
// (b, 32-row i-tile), grid 2048 x 256, p in LDS — no global P round-trip),
// but Phase A uses a DEPTH-3 software pipeline: 3 named buffer slots, fully
// unrolled, unconditional refill of row r+3 -> 12KB/wave of loads in flight
// so the compiler emits counted vmcnt instead of per-row drains.
// ---------------------------------------------------------------------------
__global__ __launch_bounds__(256, 4) void attn_kernel(const unsigned short* __restrict__ wht,
                                                      const float* __restrict__ ei,
                                                      const float* __restrict__ ej,
                                                      const float* __restrict__ bias,
                                                      const int* __restrict__ adj,
                                                      float* __restrict__ out)
{
    __shared__ __align__(16) unsigned short p_s[32][520];    // unnormalized probs
    __shared__ float ei_s[32];
    __shared__ float s_row[32];

    const int tid  = threadIdx.x;
    const int lane = tid & 63;
    const int wv   = tid >> 6;        // 0..3
    const int quad = lane >> 4;
    const int l16  = lane & 15;
    const int b    = blockIdx.x >> 4;
    const int i0   = (blockIdx.x & 15) * 32;

    const float* bp = bias + ((size_t)(b * 512 + i0 + wv * 8)) * 512;
    const int*   ap = adj + (i0 + wv * 8) * 512;

    // ---- Pipeline priming: issue loads for rows 0,1,2 of this wave ----
    floatx4 pb0[3], pb1[3];
    intx4   pm0[3], pm1[3];
#pragma unroll
    for (int s = 0; s < 3; ++s) {
        pb0[s] = *(const floatx4*)(bp + (size_t)s * 512 + lane * 4);
        pb1[s] = *(const floatx4*)(bp + (size_t)s * 512 + 256 + lane * 4);
        pm0[s] = *(const intx4*)(ap + s * 512 + lane * 4);
        pm1[s] = *(const intx4*)(ap + s * 512 + 256 + lane * 4);
    }

    const floatx4 ejv0 = *(const floatx4*)(ej + b * 512 + lane * 4);
    const floatx4 ejv1 = *(const floatx4*)(ej + b * 512 + 256 + lane * 4);
    if (tid < 32) ei_s[tid] = ei[b * 512 + i0 + tid];
    __syncthreads();

    float rsum[8];

#pragma unroll
    for (int rr = 0; rr < 8; ++rr) {
        const int s = rr % 3;          // compile-time after full unroll
        const int il = wv * 8 + rr;
        const float eiv = ei_s[il];
        float sm = 0.f;
        ushort4v o0, o1;
#pragma unroll
        for (int e = 0; e < 4; ++e) {
            float x = eiv + ejv0[e];
            x = fmaxf(x, ALPHA * x);               // leaky relu
            x += pb0[s][e];
            float p = __expf(x);                   // no max-subtraction (|x| small)
            p = (pm0[s][e] != 0) ? p : 0.f;
            sm += p;
            o0[e] = f2bf(p);
        }
#pragma unroll
        for (int e = 0; e < 4; ++e) {
            float x = eiv + ejv1[e];
            x = fmaxf(x, ALPHA * x);
            x += pb1[s][e];
            float p = __expf(x);
            p = (pm1[s][e] != 0) ? p : 0.f;
            sm += p;
            o1[e] = f2bf(p);
        }
        *(ushort4v*)&p_s[il][lane * 4]       = o0;
        *(ushort4v*)&p_s[il][256 + lane * 4] = o1;
        rsum[rr] = sm;

        // Refill slot s with row rr+3 (unconditional form; guarded by constant)
        if (rr < 5) {
            pb0[s] = *(const floatx4*)(bp + (size_t)(rr + 3) * 512 + lane * 4);
            pb1[s] = *(const floatx4*)(bp + (size_t)(rr + 3) * 512 + 256 + lane * 4);
            pm0[s] = *(const intx4*)(ap + (rr + 3) * 512 + lane * 4);
            pm1[s] = *(const intx4*)(ap + (rr + 3) * 512 + 256 + lane * 4);
        }
    }

    // Deferred row-sum reductions: 8 independent trees, pipelined
#pragma unroll
    for (int rr = 0; rr < 8; ++rr)
        for (int off = 32; off; off >>= 1)
            rsum[rr] += __shfl_xor(rsum[rr], off);
    if (lane == 0)
#pragma unroll
        for (int rr = 0; rr < 8; ++rr) s_row[wv * 8 + rr] = rsum[rr];
    __syncthreads();

    // ---- Phase B: C[32x128] = P[32x512] @ Wh[512x128], B-frags from L2, prefetched ----
    floatx4 acc[2][2];
    for (int m = 0; m < 2; ++m)
        for (int n = 0; n < 2; ++n) acc[m][n] = (floatx4)0.f;

    const unsigned short* wbase = wht + (size_t)b * 65536;
    const unsigned short* wb0 = wbase + (wv * 32 + l16) * 512 + quad * 8;
    const unsigned short* wb1 = wbase + (wv * 32 + 16 + l16) * 512 + quad * 8;
    short8 bf0 = *(const short8*)(wb0);
    short8 bf1 = *(const short8*)(wb1);
#pragma unroll
    for (int k16 = 0; k16 < 16; ++k16) {
        int ko = k16 * 32 + quad * 8;
        short8 nbf0, nbf1;
        if (k16 < 15) {
            nbf0 = *(const short8*)(wb0 + (k16 + 1) * 32);
            nbf1 = *(const short8*)(wb1 + (k16 + 1) * 32);
        }
        short8 af0 = *(const short8*)&p_s[l16][ko];
        short8 af1 = *(const short8*)&p_s[16 + l16][ko];
        acc[0][0] = __builtin_amdgcn_mfma_f32_16x16x32_bf16(af0, bf0, acc[0][0], 0, 0, 0);
        acc[0][1] = __builtin_amdgcn_mfma_f32_16x16x32_bf16(af0, bf1, acc[0][1], 0, 0, 0);
        acc[1][0] = __builtin_amdgcn_mfma_f32_16x16x32_bf16(af1, bf0, acc[1][0], 0, 0, 0);
        acc[1][1] = __builtin_amdgcn_mfma_f32_16x16x32_bf16(af1, bf1, acc[1][1], 0, 0, 0);
        bf0 = nbf0; bf1 = nbf1;
    }

    // ---- Epilogue: normalize, elu, fp32 store ----
    for (int m = 0; m < 2; ++m)
        for (int n = 0; n < 2; ++n)
            for (int r = 0; r < 4; ++r) {
                int il = m * 16 + quad * 4 + r;
                int o  = wv * 32 + n * 16 + l16;
                float v = acc[m][n][r] / s_row[il];
                v = v > 0.f ? v : (__expf(v) - 1.f);
                out[((size_t)(b * 512 + i0 + il)) * 128 + o] = v;
            }
}

// ---------------------------------------------------------------------------
extern "C" void kernel_launch(void* const* d_in, const int* in_sizes, int n_in,
                              void* d_out, int out_size, void* d_ws, size_t ws_size,
                              hipStream_t stream)
{
    const float* h    = (const float*)d_in[0];
    const float* W    = (const float*)d_in[1];
    const float* a    = (const float*)d_in[2];
    const float* bias = (const float*)d_in[3];
    const int*   adj  = (const int*)d_in[4];
    float*       out  = (float*)d_out;

    unsigned short* wht = (unsigned short*)d_ws;          // 16.78 MB bf16 Wh_t[b][o][j]
    float* ei = (float*)((char*)d_ws + 16777216);
    float* ej = ei + 65536;

    hipLaunchKernelGGL(wh_kernel,   dim3(512),  dim3(256), 0, stream, h, W, a, wht, ei, ej);
    hipLaunchKernelGGL(attn_kernel, dim3(2048), dim3(256), 0, stream, wht, ei, ej, bias, adj, out);
}

// Round 6
// 248.874 us; speedup vs baseline: 1.1849x; 1.0535x over previous
//
#include <hip/hip_runtime.h>
#include <string.h>

#define ALPHA 0.2f
// B=128, L=512, FIN=FOUT=128. Global I/O fp32; internal GEMMs bf16 MFMA.

typedef short short8 __attribute__((ext_vector_type(8)));
typedef float floatx4 __attribute__((ext_vector_type(4)));
typedef int intx4 __attribute__((ext_vector_type(4)));
typedef unsigned short ushort4v __attribute__((ext_vector_type(4)));

__device__ inline unsigned short f2bf(float f) {
    unsigned int v; __builtin_memcpy(&v, &f, 4);
    v = v + 0x7FFFu + ((v >> 16) & 1u);   // RNE
    return (unsigned short)(v >> 16);
}

__device__ inline floatx4 ntload_f4(const float* p) {
    return __builtin_nontemporal_load((const floatx4*)p);
}

// ---------------------------------------------------------------------------
// Kernel 1 (round-0 proven ~20us): Wh^T = (h @ W)^T via swapped MFMA operands.
// grid 512 x 256 threads.
// ---------------------------------------------------------------------------
__global__ __launch_bounds__(256) void wh_kernel(const float* __restrict__ h,
                                                 const float* __restrict__ W,
                                                 const float* __restrict__ a,
                                                 unsigned short* __restrict__ wht,
                                                 float* __restrict__ ei,
                                                 float* __restrict__ ej)
{
    __shared__ __align__(16) unsigned short h_s[128][136];  // [j_local][f] bf16
    __shared__ __align__(16) unsigned short w_s[128][136];  // [o][f] bf16
    __shared__ float a_s[256];
    const int tid  = threadIdx.x;
    const int lane = tid & 63;
    const int wv   = tid >> 6;
    const int quad = lane >> 4;
    const int l16  = lane & 15;
    const int r0   = blockIdx.x * 128;
    const int b    = r0 >> 9;
    const int jb   = r0 & 511;

    const float* hbase = h + (size_t)r0 * 128;
    for (int it = 0; it < 16; ++it) {
        int idx4 = it * 256 + tid;
        floatx4 v = *(const floatx4*)(hbase + idx4 * 4);
        int row = idx4 >> 5;
        int col = (idx4 & 31) * 4;
        ushort4v u;
        for (int e = 0; e < 4; ++e) u[e] = f2bf(v[e]);
        *(ushort4v*)&h_s[row][col] = u;
    }
    for (int it = 0; it < 64; ++it) {
        int idx = it * 256 + tid;
        w_s[idx & 127][idx >> 7] = f2bf(W[idx]);
    }
    a_s[tid] = a[tid];
    __syncthreads();

    floatx4 acc[8][2];
    for (int mo = 0; mo < 8; ++mo)
        for (int n = 0; n < 2; ++n) acc[mo][n] = (floatx4)0.f;

    for (int kk = 0; kk < 4; ++kk) {
        short8 bfr[2];
        for (int n = 0; n < 2; ++n)
            bfr[n] = *(const short8*)&h_s[wv * 32 + n * 16 + l16][kk * 32 + quad * 8];
        for (int mo = 0; mo < 8; ++mo) {
            short8 afr = *(const short8*)&w_s[mo * 16 + l16][kk * 32 + quad * 8];
            acc[mo][0] = __builtin_amdgcn_mfma_f32_16x16x32_bf16(afr, bfr[0], acc[mo][0], 0, 0, 0);
            acc[mo][1] = __builtin_amdgcn_mfma_f32_16x16x32_bf16(afr, bfr[1], acc[mo][1], 0, 0, 0);
        }
    }

    for (int n = 0; n < 2; ++n) {
        float si = 0.f, sj = 0.f;
        for (int mo = 0; mo < 8; ++mo)
            for (int r = 0; r < 4; ++r) {
                int o = mo * 16 + quad * 4 + r;
                float v = acc[mo][n][r];
                si += v * a_s[o];
                sj += v * a_s[128 + o];
            }
        si += __shfl_xor(si, 16); si += __shfl_xor(si, 32);
        sj += __shfl_xor(sj, 16); sj += __shfl_xor(sj, 32);
        if (quad == 0) {
            int j = jb + wv * 32 + n * 16 + l16;
            ei[b * 512 + j] = si;
            ej[b * 512 + j] = sj;
        }
    }

    for (int mo = 0; mo < 8; ++mo)
        for (int n = 0; n < 2; ++n)
            for (int r = 0; r < 4; ++r) {
                int o = mo * 16 + quad * 4 + r;
                int j = jb + wv * 32 + n * 16 + l16;
                wht[(size_t)b * 65536 + o * 512 + j] = f2bf(acc[mo][n][r]);
            }
}

// ---------------------------------------------------------------------------
// Kernel 2: scores -> softmax -> att @ Wh -> elu.
// 64-row i-tiles, 512 threads (8 waves, each wave: 8 rows Phase A — identical
// per-wave code to the proven R0 kernel — then a 16-wide o-slice in Phase B).
// XCD-aware remap: HW round-robins blockIdx%8 across XCDs, so x=bid&7 owns
// b in [x*16, x*16+16) -> per-XCD L2 working set = 16x128KB wht + 1MB adj
// (~3MB, L2-resident). Halves aggregate cache reads of wht (128KB per 64 rows
// instead of per 32) and makes them L2- instead of L3-served.
// LDS ~67KB -> 2 blk/CU = 16 waves/CU. grid 1024 x 512.
// ---------------------------------------------------------------------------
__global__ __launch_bounds__(512, 4) void attn_kernel(const unsigned short* __restrict__ wht,
                                                      const float* __restrict__ ei,
                                                      const float* __restrict__ ej,
                                                      const float* __restrict__ bias,
                                                      const int* __restrict__ adj,
                                                      float* __restrict__ out)
{
    __shared__ __align__(16) unsigned short p_s[64][520];    // unnormalized probs
    __shared__ float ei_s[64];
    __shared__ float s_row[64];

    const int tid  = threadIdx.x;
    const int lane = tid & 63;
    const int wv   = tid >> 6;        // 0..7
    const int quad = lane >> 4;
    const int l16  = lane & 15;

    // XCD-aware decode: x = bid&7 is the XCD under HW round-robin.
    const int n  = blockIdx.x;
    const int x  = n & 7;
    const int r  = n >> 3;            // 0..127
    const int b  = x * 16 + (r >> 3); // each XCD owns 16 consecutive b's
    const int i0 = (r & 7) * 64;      // 8 i-tiles of 64 rows

    const float* bp = bias + ((size_t)(b * 512 + i0 + wv * 8)) * 512;
    const int*   ap = adj + (i0 + wv * 8) * 512;
    floatx4 bb0 = ntload_f4(bp + lane * 4);          // stream-once -> nt
    floatx4 bb1 = ntload_f4(bp + 256 + lane * 4);
    intx4   mm0 = *(const intx4*)(ap + lane * 4);    // adj L2-resident
    intx4   mm1 = *(const intx4*)(ap + 256 + lane * 4);

    const floatx4 ejv0 = *(const floatx4*)(ej + b * 512 + lane * 4);
    const floatx4 ejv1 = *(const floatx4*)(ej + b * 512 + 256 + lane * 4);
    if (tid < 64) ei_s[tid] = ei[b * 512 + i0 + tid];
    __syncthreads();

    // ---- Phase A: one wave per 8 rows (proven R0 code) ----
    float rsum[8];

#pragma unroll
    for (int rr = 0; rr < 8; ++rr) {
        floatx4 nb0, nb1; intx4 nm0, nm1;
        if (rr < 7) {                              // prefetch next row
            nb0 = ntload_f4(bp + 512 + lane * 4);
            nb1 = ntload_f4(bp + 768 + lane * 4);
            nm0 = *(const intx4*)(ap + 512 + lane * 4);
            nm1 = *(const intx4*)(ap + 768 + lane * 4);
        }
        const int il = wv * 8 + rr;
        const float eiv = ei_s[il];
        float sm = 0.f;
        ushort4v p0, p1;
#pragma unroll
        for (int e = 0; e < 4; ++e) {
            float xv = eiv + ejv0[e];
            xv = fmaxf(xv, ALPHA * xv);            // leaky relu
            xv += bb0[e];
            float p = __expf(xv);                  // no max-subtraction (|x| small)
            p = (mm0[e] != 0) ? p : 0.f;
            sm += p;
            p0[e] = f2bf(p);
        }
#pragma unroll
        for (int e = 0; e < 4; ++e) {
            float xv = eiv + ejv1[e];
            xv = fmaxf(xv, ALPHA * xv);
            xv += bb1[e];
            float p = __expf(xv);
            p = (mm1[e] != 0) ? p : 0.f;
            sm += p;
            p1[e] = f2bf(p);
        }
        *(ushort4v*)&p_s[il][lane * 4]       = p0;
        *(ushort4v*)&p_s[il][256 + lane * 4] = p1;
        rsum[rr] = sm;
        bb0 = nb0; bb1 = nb1; mm0 = nm0; mm1 = nm1;
        bp += 512; ap += 512;
    }

    // Deferred row-sum reductions: 8 independent trees, pipelined
#pragma unroll
    for (int rr = 0; rr < 8; ++rr)
        for (int off = 32; off; off >>= 1)
            rsum[rr] += __shfl_xor(rsum[rr], off);
    if (lane == 0)
#pragma unroll
        for (int rr = 0; rr < 8; ++rr) s_row[wv * 8 + rr] = rsum[rr];
    __syncthreads();

    // ---- Phase B: C[64x16] per wave = P[64x512] @ Wh[512x16-slice].
    // Per block, wht[b] (128KB) is read exactly once, L2-served (XCD remap).
    floatx4 acc[4];
#pragma unroll
    for (int m = 0; m < 4; ++m) acc[m] = (floatx4)0.f;

    const unsigned short* wb = wht + (size_t)b * 65536 + (wv * 16 + l16) * 512 + quad * 8;
    short8 bf = *(const short8*)(wb);
#pragma unroll
    for (int k16 = 0; k16 < 16; ++k16) {
        int ko = k16 * 32 + quad * 8;
        short8 nbf;
        if (k16 < 15) nbf = *(const short8*)(wb + (k16 + 1) * 32);
        short8 af0 = *(const short8*)&p_s[l16][ko];
        short8 af1 = *(const short8*)&p_s[16 + l16][ko];
        short8 af2 = *(const short8*)&p_s[32 + l16][ko];
        short8 af3 = *(const short8*)&p_s[48 + l16][ko];
        acc[0] = __builtin_amdgcn_mfma_f32_16x16x32_bf16(af0, bf, acc[0], 0, 0, 0);
        acc[1] = __builtin_amdgcn_mfma_f32_16x16x32_bf16(af1, bf, acc[1], 0, 0, 0);
        acc[2] = __builtin_amdgcn_mfma_f32_16x16x32_bf16(af2, bf, acc[2], 0, 0, 0);
        acc[3] = __builtin_amdgcn_mfma_f32_16x16x32_bf16(af3, bf, acc[3], 0, 0, 0);
        bf = nbf;
    }

    // ---- Epilogue: normalize, elu, fp32 nontemporal store ----
#pragma unroll
    for (int m = 0; m < 4; ++m)
#pragma unroll
        for (int rr2 = 0; rr2 < 4; ++rr2) {
            int il = m * 16 + quad * 4 + rr2;
            int o  = wv * 16 + l16;
            float v = acc[m][rr2] / s_row[il];
            v = v > 0.f ? v : (__expf(v) - 1.f);
            __builtin_nontemporal_store(v, &out[((size_t)(b * 512 + i0 + il)) * 128 + o]);
        }
}

// ---------------------------------------------------------------------------
extern "C" void kernel_launch(void* const* d_in, const int* in_sizes, int n_in,
                              void* d_out, int out_size, void* d_ws, size_t ws_size,
                              hipStream_t stream)
{
    const float* h    = (const float*)d_in[0];
    const float* W    = (const float*)d_in[1];
    const float* a    = (const float*)d_in[2];
    const float* bias = (const float*)d_in[3];
    const int*   adj  = (const int*)d_in[4];
    float*       out  = (float*)d_out;

    unsigned short* wht = (unsigned short*)d_ws;          // 16.78 MB bf16 Wh_t[b][o][j]
    float* ei = (float*)((char*)d_ws + 16777216);
    float* ej = ei + 65536;

    hipLaunchKernelGGL(wh_kernel,   dim3(512),  dim3(256), 0, stream, h, W, a, wht, ei, ej);
    hipLaunchKernelGGL(attn_kernel, dim3(1024), dim3(512), 0, stream, wht, ei, ej, bias, adj, out);
}

// Round 7
// 247.402 us; speedup vs baseline: 1.1920x; 1.0060x over previous
//
#include <hip/hip_runtime.h>
#include <string.h>

#define ALPHA 0.2f
// B=128, L=512, FIN=FOUT=128. Global I/O fp32; internal GEMMs bf16 MFMA.

typedef short short8 __attribute__((ext_vector_type(8)));
typedef float floatx4 __attribute__((ext_vector_type(4)));
typedef int intx4 __attribute__((ext_vector_type(4)));
typedef unsigned short ushort4v __attribute__((ext_vector_type(4)));

__device__ inline unsigned short f2bf(float f) {
    unsigned int v; __builtin_memcpy(&v, &f, 4);
    v = v + 0x7FFFu + ((v >> 16) & 1u);   // RNE
    return (unsigned short)(v >> 16);
}

__device__ inline floatx4 ntload_f4(const float* p) {
    return __builtin_nontemporal_load((const floatx4*)p);
}

// ---------------------------------------------------------------------------
// Kernel 0: pack adj[512][512] int32 -> bitmask u64[512][8] (512 bits/row).
// One wave per row via ballot; 4 rows/block, grid 128. ~1MB read, 32KB write.
// Purpose: Phase A of attn reads 1 cache line per row for the mask instead
// of 32 (adj rows were 2KB) -> cuts per-row request count 64 -> 33.
// ---------------------------------------------------------------------------
__global__ __launch_bounds__(256) void mask_kernel(const int* __restrict__ adj,
                                                   unsigned long long* __restrict__ mask)
{
    const int lane = threadIdx.x & 63;
    const int wv   = threadIdx.x >> 6;
    const int row  = blockIdx.x * 4 + wv;
    const int* ar  = adj + row * 512;
    unsigned long long w0, w1, w2, w3, w4, w5, w6, w7;
    w0 = __ballot(ar[0 * 64 + lane] != 0);
    w1 = __ballot(ar[1 * 64 + lane] != 0);
    w2 = __ballot(ar[2 * 64 + lane] != 0);
    w3 = __ballot(ar[3 * 64 + lane] != 0);
    w4 = __ballot(ar[4 * 64 + lane] != 0);
    w5 = __ballot(ar[5 * 64 + lane] != 0);
    w6 = __ballot(ar[6 * 64 + lane] != 0);
    w7 = __ballot(ar[7 * 64 + lane] != 0);
    if (lane == 0) {
        unsigned long long* mr = mask + row * 8;
        mr[0] = w0; mr[1] = w1; mr[2] = w2; mr[3] = w3;
        mr[4] = w4; mr[5] = w5; mr[6] = w6; mr[7] = w7;
    }
}

// ---------------------------------------------------------------------------
// Kernel 1 (round-0 proven ~20us): Wh^T = (h @ W)^T via swapped MFMA operands.
// grid 512 x 256 threads.
// ---------------------------------------------------------------------------
__global__ __launch_bounds__(256) void wh_kernel(const float* __restrict__ h,
                                                 const float* __restrict__ W,
                                                 const float* __restrict__ a,
                                                 unsigned short* __restrict__ wht,
                                                 float* __restrict__ ei,
                                                 float* __restrict__ ej)
{
    __shared__ __align__(16) unsigned short h_s[128][136];  // [j_local][f] bf16
    __shared__ __align__(16) unsigned short w_s[128][136];  // [o][f] bf16
    __shared__ float a_s[256];
    const int tid  = threadIdx.x;
    const int lane = tid & 63;
    const int wv   = tid >> 6;
    const int quad = lane >> 4;
    const int l16  = lane & 15;
    const int r0   = blockIdx.x * 128;
    const int b    = r0 >> 9;
    const int jb   = r0 & 511;

    const float* hbase = h + (size_t)r0 * 128;
    for (int it = 0; it < 16; ++it) {
        int idx4 = it * 256 + tid;
        floatx4 v = *(const floatx4*)(hbase + idx4 * 4);
        int row = idx4 >> 5;
        int col = (idx4 & 31) * 4;
        ushort4v u;
        for (int e = 0; e < 4; ++e) u[e] = f2bf(v[e]);
        *(ushort4v*)&h_s[row][col] = u;
    }
    for (int it = 0; it < 64; ++it) {
        int idx = it * 256 + tid;
        w_s[idx & 127][idx >> 7] = f2bf(W[idx]);
    }
    a_s[tid] = a[tid];
    __syncthreads();

    floatx4 acc[8][2];
    for (int mo = 0; mo < 8; ++mo)
        for (int n = 0; n < 2; ++n) acc[mo][n] = (floatx4)0.f;

    for (int kk = 0; kk < 4; ++kk) {
        short8 bfr[2];
        for (int n = 0; n < 2; ++n)
            bfr[n] = *(const short8*)&h_s[wv * 32 + n * 16 + l16][kk * 32 + quad * 8];
        for (int mo = 0; mo < 8; ++mo) {
            short8 afr = *(const short8*)&w_s[mo * 16 + l16][kk * 32 + quad * 8];
            acc[mo][0] = __builtin_amdgcn_mfma_f32_16x16x32_bf16(afr, bfr[0], acc[mo][0], 0, 0, 0);
            acc[mo][1] = __builtin_amdgcn_mfma_f32_16x16x32_bf16(afr, bfr[1], acc[mo][1], 0, 0, 0);
        }
    }

    for (int n = 0; n < 2; ++n) {
        float si = 0.f, sj = 0.f;
        for (int mo = 0; mo < 8; ++mo)
            for (int r = 0; r < 4; ++r) {
                int o = mo * 16 + quad * 4 + r;
                float v = acc[mo][n][r];
                si += v * a_s[o];
                sj += v * a_s[128 + o];
            }
        si += __shfl_xor(si, 16); si += __shfl_xor(si, 32);
        sj += __shfl_xor(sj, 16); sj += __shfl_xor(sj, 32);
        if (quad == 0) {
            int j = jb + wv * 32 + n * 16 + l16;
            ei[b * 512 + j] = si;
            ej[b * 512 + j] = sj;
        }
    }

    for (int mo = 0; mo < 8; ++mo)
        for (int n = 0; n < 2; ++n)
            for (int r = 0; r < 4; ++r) {
                int o = mo * 16 + quad * 4 + r;
                int j = jb + wv * 32 + n * 16 + l16;
                wht[(size_t)b * 65536 + o * 512 + j] = f2bf(acc[mo][n][r]);
            }
}

// ---------------------------------------------------------------------------
// Kernel 2 (R6 winning structure + bitmask adj): 64-row i-tiles, 512 threads,
// XCD-aware remap (each XCD owns 16 consecutive b's -> wht/mask L2-resident),
// Phase A one wave per 8 rows with depth-1 prefetch; adj via 2 x 4B mask
// loads (1 line/row) instead of 2 x 16B/lane int loads (32 lines/row).
// LDS ~67KB -> 2 blk/CU = 16 waves/CU. grid 1024 x 512.
// ---------------------------------------------------------------------------
__global__ __launch_bounds__(512, 4) void attn_kernel(const unsigned short* __restrict__ wht,
                                                      const float* __restrict__ ei,
                                                      const float* __restrict__ ej,
                                                      const float* __restrict__ bias,
                                                      const unsigned* __restrict__ mask32,
                                                      float* __restrict__ out)
{
    __shared__ __align__(16) unsigned short p_s[64][520];    // unnormalized probs
    __shared__ float ei_s[64];
    __shared__ float s_row[64];

    const int tid  = threadIdx.x;
    const int lane = tid & 63;
    const int wv   = tid >> 6;        // 0..7
    const int quad = lane >> 4;
    const int l16  = lane & 15;

    // XCD-aware decode: x = bid&7 is the XCD under HW round-robin.
    const int n  = blockIdx.x;
    const int x  = n & 7;
    const int r  = n >> 3;            // 0..127
    const int b  = x * 16 + (r >> 3); // each XCD owns 16 consecutive b's
    const int i0 = (r & 7) * 64;      // 8 i-tiles of 64 rows

    const float*    bp = bias + ((size_t)(b * 512 + i0 + wv * 8)) * 512;
    const unsigned* mp = mask32 + (i0 + wv * 8) * 16;
    const int mw = lane >> 3;                 // word index 0..7 (8 lanes share)
    const int ms = (lane & 7) * 4;            // nibble shift within word
    floatx4 bb0 = ntload_f4(bp + lane * 4);   // bias streamed once -> nt
    floatx4 bb1 = ntload_f4(bp + 256 + lane * 4);
    unsigned cm0 = mp[mw];                    // bits j = lane*4..+3 in nibble
    unsigned cm1 = mp[8 + mw];                // bits j = 256+lane*4..+3

    const floatx4 ejv0 = *(const floatx4*)(ej + b * 512 + lane * 4);
    const floatx4 ejv1 = *(const floatx4*)(ej + b * 512 + 256 + lane * 4);
    if (tid < 64) ei_s[tid] = ei[b * 512 + i0 + tid];
    __syncthreads();

    // ---- Phase A: one wave per 8 rows, depth-1 prefetch ----
    float rsum[8];

#pragma unroll
    for (int rr = 0; rr < 8; ++rr) {
        floatx4 nb0, nb1; unsigned nm0, nm1;
        if (rr < 7) {                              // prefetch next row
            nb0 = ntload_f4(bp + 512 + lane * 4);
            nb1 = ntload_f4(bp + 768 + lane * 4);
            nm0 = mp[16 + mw];
            nm1 = mp[24 + mw];
        }
        const int il = wv * 8 + rr;
        const float eiv = ei_s[il];
        const unsigned nib0 = (cm0 >> ms) & 0xFu;
        const unsigned nib1 = (cm1 >> ms) & 0xFu;
        float sm = 0.f;
        ushort4v p0, p1;
#pragma unroll
        for (int e = 0; e < 4; ++e) {
            float xv = eiv + ejv0[e];
            xv = fmaxf(xv, ALPHA * xv);            // leaky relu
            xv += bb0[e];
            float p = __expf(xv);                  // no max-subtraction (|x| small)
            p = (nib0 & (1u << e)) ? p : 0.f;
            sm += p;
            p0[e] = f2bf(p);
        }
#pragma unroll
        for (int e = 0; e < 4; ++e) {
            float xv = eiv + ejv1[e];
            xv = fmaxf(xv, ALPHA * xv);
            xv += bb1[e];
            float p = __expf(xv);
            p = (nib1 & (1u << e)) ? p : 0.f;
            sm += p;
            p1[e] = f2bf(p);
        }
        *(ushort4v*)&p_s[il][lane * 4]       = p0;
        *(ushort4v*)&p_s[il][256 + lane * 4] = p1;
        rsum[rr] = sm;
        bb0 = nb0; bb1 = nb1; cm0 = nm0; cm1 = nm1;
        bp += 512; mp += 16;
    }

    // Deferred row-sum reductions: 8 independent trees, pipelined
#pragma unroll
    for (int rr = 0; rr < 8; ++rr)
        for (int off = 32; off; off >>= 1)
            rsum[rr] += __shfl_xor(rsum[rr], off);
    if (lane == 0)
#pragma unroll
        for (int rr = 0; rr < 8; ++rr) s_row[wv * 8 + rr] = rsum[rr];
    __syncthreads();

    // ---- Phase B: C[64x16] per wave = P[64x512] @ Wh[512x16-slice].
    // Per block, wht[b] (128KB) is read exactly once, L2-served (XCD remap).
    floatx4 acc[4];
#pragma unroll
    for (int m = 0; m < 4; ++m) acc[m] = (floatx4)0.f;

    const unsigned short* wb = wht + (size_t)b * 65536 + (wv * 16 + l16) * 512 + quad * 8;
    short8 bf = *(const short8*)(wb);
#pragma unroll
    for (int k16 = 0; k16 < 16; ++k16) {
        int ko = k16 * 32 + quad * 8;
        short8 nbf;
        if (k16 < 15) nbf = *(const short8*)(wb + (k16 + 1) * 32);
        short8 af0 = *(const short8*)&p_s[l16][ko];
        short8 af1 = *(const short8*)&p_s[16 + l16][ko];
        short8 af2 = *(const short8*)&p_s[32 + l16][ko];
        short8 af3 = *(const short8*)&p_s[48 + l16][ko];
        acc[0] = __builtin_amdgcn_mfma_f32_16x16x32_bf16(af0, bf, acc[0], 0, 0, 0);
        acc[1] = __builtin_amdgcn_mfma_f32_16x16x32_bf16(af1, bf, acc[1], 0, 0, 0);
        acc[2] = __builtin_amdgcn_mfma_f32_16x16x32_bf16(af2, bf, acc[2], 0, 0, 0);
        acc[3] = __builtin_amdgcn_mfma_f32_16x16x32_bf16(af3, bf, acc[3], 0, 0, 0);
        bf = nbf;
    }

    // ---- Epilogue: normalize, elu, fp32 nontemporal store ----
#pragma unroll
    for (int m = 0; m < 4; ++m)
#pragma unroll
        for (int rr2 = 0; rr2 < 4; ++rr2) {
            int il = m * 16 + quad * 4 + rr2;
            int o  = wv * 16 + l16;
            float v = acc[m][rr2] / s_row[il];
            v = v > 0.f ? v : (__expf(v) - 1.f);
            __builtin_nontemporal_store(v, &out[((size_t)(b * 512 + i0 + il)) * 128 + o]);
        }
}

// ---------------------------------------------------------------------------
extern "C" void kernel_launch(void* const* d_in, const int* in_sizes, int n_in,
                              void* d_out, int out_size, void* d_ws, size_t ws_size,
                              hipStream_t stream)
{
    const float* h    = (const float*)d_in[0];
    const float* W    = (const float*)d_in[1];
    const float* a    = (const float*)d_in[2];
    const float* bias = (const float*)d_in[3];
    const int*   adj  = (const int*)d_in[4];
    float*       out  = (float*)d_out;

    unsigned short* wht = (unsigned short*)d_ws;          // 16.78 MB bf16 Wh_t[b][o][j]
    float* ei = (float*)((char*)d_ws + 16777216);         // 256 KB
    float* ej = ei + 65536;                               // 256 KB
    unsigned long long* mask = (unsigned long long*)((char*)d_ws + 17301504); // 32 KB

    hipLaunchKernelGGL(mask_kernel, dim3(128),  dim3(256), 0, stream, adj, mask);
    hipLaunchKernelGGL(wh_kernel,   dim3(512),  dim3(256), 0, stream, h, W, a, wht, ei, ej);
    hipLaunchKernelGGL(attn_kernel, dim3(1024), dim3(512), 0, stream, wht, ei, ej, bias,
                       (const unsigned*)mask, out);
}

// Round 8
// 245.364 us; speedup vs baseline: 1.2019x; 1.0083x over previous
//
#include <hip/hip_runtime.h>
#include <string.h>

#define ALPHA 0.2f
// B=128, L=512, FIN=FOUT=128. Global I/O fp32; internal GEMMs bf16 MFMA.

typedef short short8 __attribute__((ext_vector_type(8)));
typedef float floatx4 __attribute__((ext_vector_type(4)));
typedef unsigned short ushort4v __attribute__((ext_vector_type(4)));

__device__ inline unsigned short f2bf(float f) {
    unsigned int v; __builtin_memcpy(&v, &f, 4);
    v = v + 0x7FFFu + ((v >> 16) & 1u);   // RNE
    return (unsigned short)(v >> 16);
}

__device__ inline floatx4 ntload_f4(const float* p) {
    return __builtin_nontemporal_load((const floatx4*)p);
}

// ---------------------------------------------------------------------------
// Kernel 1: Wh^T = (h @ W)^T. v2: only W staged in LDS (35KB -> 4 blk/CU,
// 16 waves/CU, was 8); h fragments read global->register (each consumed by
// exactly one wave; lines L2-shared across quads). Mask pack folded in
// (blocks 0..127 pack 4 adj rows each). grid 512 x 256.
// ---------------------------------------------------------------------------
__global__ __launch_bounds__(256, 4) void wh_kernel(const float* __restrict__ h,
                                                    const float* __restrict__ W,
                                                    const float* __restrict__ a,
                                                    const int* __restrict__ adj,
                                                    unsigned short* __restrict__ wht,
                                                    float* __restrict__ ei,
                                                    float* __restrict__ ej,
                                                    unsigned long long* __restrict__ mask)
{
    __shared__ __align__(16) unsigned short w_s[128][136];  // [o][f] bf16
    __shared__ float a_s[256];
    const int tid  = threadIdx.x;
    const int lane = tid & 63;
    const int wv   = tid >> 6;
    const int quad = lane >> 4;
    const int l16  = lane & 15;
    const int r0   = blockIdx.x * 128;
    const int b    = r0 >> 9;
    const int jb   = r0 & 511;

    for (int it = 0; it < 64; ++it) {
        int idx = it * 256 + tid;
        w_s[idx & 127][idx >> 7] = f2bf(W[idx]);
    }
    a_s[tid] = a[tid];

    // ---- folded mask pack: blocks 0..127, one adj row per wave ----
    if (blockIdx.x < 128) {
        const int row = blockIdx.x * 4 + wv;
        const int* ar = adj + row * 512;
        unsigned long long wbits[8];
#pragma unroll
        for (int q = 0; q < 8; ++q) wbits[q] = __ballot(ar[q * 64 + lane] != 0);
        if (lane == 0) {
            unsigned long long* mr = mask + row * 8;
#pragma unroll
            for (int q = 0; q < 8; ++q) mr[q] = wbits[q];
        }
    }
    __syncthreads();

    // h direct: row r0 + wv*32 + n*16 + l16, cols kk*32 + quad*8 .. +7
    const float* hp0 = h + (size_t)(r0 + wv * 32 + l16) * 128 + quad * 8;
    const float* hp1 = hp0 + 16 * 128;

    floatx4 acc[8][2];
    for (int mo = 0; mo < 8; ++mo)
        for (int n = 0; n < 2; ++n) acc[mo][n] = (floatx4)0.f;

    floatx4 c00 = *(const floatx4*)(hp0);
    floatx4 c01 = *(const floatx4*)(hp0 + 4);
    floatx4 c10 = *(const floatx4*)(hp1);
    floatx4 c11 = *(const floatx4*)(hp1 + 4);
#pragma unroll
    for (int kk = 0; kk < 4; ++kk) {
        floatx4 n00, n01, n10, n11;
        if (kk < 3) {
            n00 = *(const floatx4*)(hp0 + (kk + 1) * 32);
            n01 = *(const floatx4*)(hp0 + (kk + 1) * 32 + 4);
            n10 = *(const floatx4*)(hp1 + (kk + 1) * 32);
            n11 = *(const floatx4*)(hp1 + (kk + 1) * 32 + 4);
        }
        short8 bfr0, bfr1;
#pragma unroll
        for (int e = 0; e < 4; ++e) {
            bfr0[e]     = (short)f2bf(c00[e]);
            bfr0[4 + e] = (short)f2bf(c01[e]);
            bfr1[e]     = (short)f2bf(c10[e]);
            bfr1[4 + e] = (short)f2bf(c11[e]);
        }
#pragma unroll
        for (int mo = 0; mo < 8; ++mo) {
            short8 afr = *(const short8*)&w_s[mo * 16 + l16][kk * 32 + quad * 8];
            acc[mo][0] = __builtin_amdgcn_mfma_f32_16x16x32_bf16(afr, bfr0, acc[mo][0], 0, 0, 0);
            acc[mo][1] = __builtin_amdgcn_mfma_f32_16x16x32_bf16(afr, bfr1, acc[mo][1], 0, 0, 0);
        }
        c00 = n00; c01 = n01; c10 = n10; c11 = n11;
    }

    for (int n = 0; n < 2; ++n) {
        float si = 0.f, sj = 0.f;
        for (int mo = 0; mo < 8; ++mo)
            for (int r = 0; r < 4; ++r) {
                int o = mo * 16 + quad * 4 + r;
                float v = acc[mo][n][r];
                si += v * a_s[o];
                sj += v * a_s[128 + o];
            }
        si += __shfl_xor(si, 16); si += __shfl_xor(si, 32);
        sj += __shfl_xor(sj, 16); sj += __shfl_xor(sj, 32);
        if (quad == 0) {
            int j = jb + wv * 32 + n * 16 + l16;
            ei[b * 512 + j] = si;
            ej[b * 512 + j] = sj;
        }
    }

    for (int mo = 0; mo < 8; ++mo)
        for (int n = 0; n < 2; ++n)
            for (int r = 0; r < 4; ++r) {
                int o = mo * 16 + quad * 4 + r;
                int j = jb + wv * 32 + n * 16 + l16;
                wht[(size_t)b * 65536 + o * 512 + j] = f2bf(acc[mo][n][r]);
            }
}

// ---------------------------------------------------------------------------
// Kernel 2 (persistent 2-tile): grid 512 = 2 blk/CU x 256 CU, one generation.
// Each block: two 64-row i-tiles of the same b. After tile-0 Phase A, issue
// tile-1's bias/mask rows 0..3 into registers (depth-4), run tile-0 Phase B
// (wht from L2, XCD-resident) + epilogue, barrier, then tile-1 Phase A starts
// from registers. HBM prefetch flies under Phase B -> phases overlap.
// LDS ~67KB. 512 threads, launch_bounds(512,4) (<=128 VGPR).
// ---------------------------------------------------------------------------
__global__ __launch_bounds__(512, 4) void attn_kernel(const unsigned short* __restrict__ wht,
                                                      const float* __restrict__ ei,
                                                      const float* __restrict__ ej,
                                                      const float* __restrict__ bias,
                                                      const unsigned* __restrict__ mask32,
                                                      float* __restrict__ out)
{
    __shared__ __align__(16) unsigned short p_s[64][520];
    __shared__ float ei_s[2][64];
    __shared__ float s_row[64];

    const int tid  = threadIdx.x;
    const int lane = tid & 63;
    const int wv   = tid >> 6;        // 0..7
    const int quad = lane >> 4;
    const int l16  = lane & 15;

    // XCD-aware decode: x = bid&7 is the XCD under HW round-robin.
    const int x  = blockIdx.x & 7;
    const int r2 = blockIdx.x >> 3;   // 0..63
    const int bl = r2 >> 2;           // 0..15
    const int tp = r2 & 3;            // 0..3
    const int b  = x * 16 + bl;
    const int i0 = (tp * 2) * 64;
    const int i1 = i0 + 64;

    const int mw = lane >> 3;
    const int ms = (lane & 7) * 4;

    const float*    bp = bias + ((size_t)(b * 512 + i0 + wv * 8)) * 512;
    const unsigned* mp = mask32 + (i0 + wv * 8) * 16;
    floatx4 bb0 = ntload_f4(bp + lane * 4);
    floatx4 bb1 = ntload_f4(bp + 256 + lane * 4);
    unsigned cm0 = mp[mw];
    unsigned cm1 = mp[8 + mw];

    const floatx4 ejv0 = *(const floatx4*)(ej + b * 512 + lane * 4);
    const floatx4 ejv1 = *(const floatx4*)(ej + b * 512 + 256 + lane * 4);
    if (tid < 64) ei_s[0][tid] = ei[b * 512 + i0 + tid];
    else if (tid < 128) ei_s[1][tid - 64] = ei[b * 512 + i1 + (tid - 64)];
    __syncthreads();

    float rsum[8];

    // ================= TILE 0: Phase A (proven depth-1 loop) =================
#pragma unroll
    for (int rr = 0; rr < 8; ++rr) {
        floatx4 nb0, nb1; unsigned nm0, nm1;
        if (rr < 7) {
            nb0 = ntload_f4(bp + 512 + lane * 4);
            nb1 = ntload_f4(bp + 768 + lane * 4);
            nm0 = mp[16 + mw];
            nm1 = mp[24 + mw];
        }
        const int il = wv * 8 + rr;
        const float eiv = ei_s[0][il];
        const unsigned nib0 = (cm0 >> ms) & 0xFu;
        const unsigned nib1 = (cm1 >> ms) & 0xFu;
        float sm = 0.f;
        ushort4v p0, p1;
#pragma unroll
        for (int e = 0; e < 4; ++e) {
            float xv = eiv + ejv0[e];
            xv = fmaxf(xv, ALPHA * xv);
            xv += bb0[e];
            float p = __expf(xv);
            p = (nib0 & (1u << e)) ? p : 0.f;
            sm += p;
            p0[e] = f2bf(p);
        }
#pragma unroll
        for (int e = 0; e < 4; ++e) {
            float xv = eiv + ejv1[e];
            xv = fmaxf(xv, ALPHA * xv);
            xv += bb1[e];
            float p = __expf(xv);
            p = (nib1 & (1u << e)) ? p : 0.f;
            sm += p;
            p1[e] = f2bf(p);
        }
        *(ushort4v*)&p_s[il][lane * 4]       = p0;
        *(ushort4v*)&p_s[il][256 + lane * 4] = p1;
        rsum[rr] = sm;
        bb0 = nb0; bb1 = nb1; cm0 = nm0; cm1 = nm1;
        bp += 512; mp += 16;
    }

#pragma unroll
    for (int rr = 0; rr < 8; ++rr)
        for (int off = 32; off; off >>= 1)
            rsum[rr] += __shfl_xor(rsum[rr], off);
    if (lane == 0)
#pragma unroll
        for (int rr = 0; rr < 8; ++rr) s_row[wv * 8 + rr] = rsum[rr];
    __syncthreads();                                   // b1: p_s/s_row ready

    // ---- Cross-tile prefetch: tile-1 rows 0..3 into registers (depth-4) ----
    const float*    bp1 = bias + ((size_t)(b * 512 + i1 + wv * 8)) * 512;
    const unsigned* mp1 = mask32 + (i1 + wv * 8) * 16;
    floatx4 q0[4], q1[4]; unsigned qm0[4], qm1[4];
#pragma unroll
    for (int rr = 0; rr < 4; ++rr) {
        q0[rr]  = ntload_f4(bp1 + (size_t)rr * 512 + lane * 4);
        q1[rr]  = ntload_f4(bp1 + (size_t)rr * 512 + 256 + lane * 4);
        qm0[rr] = mp1[rr * 16 + mw];
        qm1[rr] = mp1[rr * 16 + 8 + mw];
    }

    // ================= TILE 0: Phase B =================
    floatx4 acc[4];
#pragma unroll
    for (int m = 0; m < 4; ++m) acc[m] = (floatx4)0.f;

    const unsigned short* wb = wht + (size_t)b * 65536 + (wv * 16 + l16) * 512 + quad * 8;
    short8 bf = *(const short8*)(wb);
#pragma unroll
    for (int k16 = 0; k16 < 16; ++k16) {
        int ko = k16 * 32 + quad * 8;
        short8 nbf;
        if (k16 < 15) nbf = *(const short8*)(wb + (k16 + 1) * 32);
        short8 af0 = *(const short8*)&p_s[l16][ko];
        short8 af1 = *(const short8*)&p_s[16 + l16][ko];
        short8 af2 = *(const short8*)&p_s[32 + l16][ko];
        short8 af3 = *(const short8*)&p_s[48 + l16][ko];
        acc[0] = __builtin_amdgcn_mfma_f32_16x16x32_bf16(af0, bf, acc[0], 0, 0, 0);
        acc[1] = __builtin_amdgcn_mfma_f32_16x16x32_bf16(af1, bf, acc[1], 0, 0, 0);
        acc[2] = __builtin_amdgcn_mfma_f32_16x16x32_bf16(af2, bf, acc[2], 0, 0, 0);
        acc[3] = __builtin_amdgcn_mfma_f32_16x16x32_bf16(af3, bf, acc[3], 0, 0, 0);
        bf = nbf;
    }

    // epilogue tile 0 (reads s_row before b2)
#pragma unroll
    for (int m = 0; m < 4; ++m)
#pragma unroll
        for (int rr2 = 0; rr2 < 4; ++rr2) {
            int il = m * 16 + quad * 4 + rr2;
            int o  = wv * 16 + l16;
            float v = acc[m][rr2] / s_row[il];
            v = v > 0.f ? v : (__expf(v) - 1.f);
            __builtin_nontemporal_store(v, &out[((size_t)(b * 512 + i0 + il)) * 128 + o]);
        }
    __syncthreads();                                   // b2: p_s/s_row free

    // ================= TILE 1: Phase A (rows 0..3 from regs, depth-4) =======
#pragma unroll
    for (int rr = 0; rr < 8; ++rr) {
        const int s = rr & 3;
        floatx4 cb0 = q0[s], cb1 = q1[s];
        unsigned m0 = qm0[s], m1 = qm1[s];
        if (rr < 4) {
            q0[s]  = ntload_f4(bp1 + (size_t)(rr + 4) * 512 + lane * 4);
            q1[s]  = ntload_f4(bp1 + (size_t)(rr + 4) * 512 + 256 + lane * 4);
            qm0[s] = mp1[(rr + 4) * 16 + mw];
            qm1[s] = mp1[(rr + 4) * 16 + 8 + mw];
        }
        const int il = wv * 8 + rr;
        const float eiv = ei_s[1][il];
        const unsigned nib0 = (m0 >> ms) & 0xFu;
        const unsigned nib1 = (m1 >> ms) & 0xFu;
        float sm = 0.f;
        ushort4v p0, p1;
#pragma unroll
        for (int e = 0; e < 4; ++e) {
            float xv = eiv + ejv0[e];
            xv = fmaxf(xv, ALPHA * xv);
            xv += cb0[e];
            float p = __expf(xv);
            p = (nib0 & (1u << e)) ? p : 0.f;
            sm += p;
            p0[e] = f2bf(p);
        }
#pragma unroll
        for (int e = 0; e < 4; ++e) {
            float xv = eiv + ejv1[e];
            xv = fmaxf(xv, ALPHA * xv);
            xv += cb1[e];
            float p = __expf(xv);
            p = (nib1 & (1u << e)) ? p : 0.f;
            sm += p;
            p1[e] = f2bf(p);
        }
        *(ushort4v*)&p_s[il][lane * 4]       = p0;
        *(ushort4v*)&p_s[il][256 + lane * 4] = p1;
        rsum[rr] = sm;
    }

#pragma unroll
    for (int rr = 0; rr < 8; ++rr)
        for (int off = 32; off; off >>= 1)
            rsum[rr] += __shfl_xor(rsum[rr], off);
    if (lane == 0)
#pragma unroll
        for (int rr = 0; rr < 8; ++rr) s_row[wv * 8 + rr] = rsum[rr];
    __syncthreads();                                   // b3

    // ================= TILE 1: Phase B + epilogue =================
#pragma unroll
    for (int m = 0; m < 4; ++m) acc[m] = (floatx4)0.f;

    bf = *(const short8*)(wb);
#pragma unroll
    for (int k16 = 0; k16 < 16; ++k16) {
        int ko = k16 * 32 + quad * 8;
        short8 nbf;
        if (k16 < 15) nbf = *(const short8*)(wb + (k16 + 1) * 32);
        short8 af0 = *(const short8*)&p_s[l16][ko];
        short8 af1 = *(const short8*)&p_s[16 + l16][ko];
        short8 af2 = *(const short8*)&p_s[32 + l16][ko];
        short8 af3 = *(const short8*)&p_s[48 + l16][ko];
        acc[0] = __builtin_amdgcn_mfma_f32_16x16x32_bf16(af0, bf, acc[0], 0, 0, 0);
        acc[1] = __builtin_amdgcn_mfma_f32_16x16x32_bf16(af1, bf, acc[1], 0, 0, 0);
        acc[2] = __builtin_amdgcn_mfma_f32_16x16x32_bf16(af2, bf, acc[2], 0, 0, 0);
        acc[3] = __builtin_amdgcn_mfma_f32_16x16x32_bf16(af3, bf, acc[3], 0, 0, 0);
        bf = nbf;
    }

#pragma unroll
    for (int m = 0; m < 4; ++m)
#pragma unroll
        for (int rr2 = 0; rr2 < 4; ++rr2) {
            int il = m * 16 + quad * 4 + rr2;
            int o  = wv * 16 + l16;
            float v = acc[m][rr2] / s_row[il];
            v = v > 0.f ? v : (__expf(v) - 1.f);
            __builtin_nontemporal_store(v, &out[((size_t)(b * 512 + i1 + il)) * 128 + o]);
        }
}

// ---------------------------------------------------------------------------
extern "C" void kernel_launch(void* const* d_in, const int* in_sizes, int n_in,
                              void* d_out, int out_size, void* d_ws, size_t ws_size,
                              hipStream_t stream)
{
    const float* h    = (const float*)d_in[0];
    const float* W    = (const float*)d_in[1];
    const float* a    = (const float*)d_in[2];
    const float* bias = (const float*)d_in[3];
    const int*   adj  = (const int*)d_in[4];
    float*       out  = (float*)d_out;

    unsigned short* wht = (unsigned short*)d_ws;          // 16.78 MB bf16 Wh_t[b][o][j]
    float* ei = (float*)((char*)d_ws + 16777216);         // 256 KB
    float* ej = ei + 65536;                               // 256 KB
    unsigned long long* mask = (unsigned long long*)((char*)d_ws + 17301504); // 32 KB

    hipLaunchKernelGGL(wh_kernel,   dim3(512), dim3(256), 0, stream, h, W, a, adj, wht, ei, ej, mask);
    hipLaunchKernelGGL(attn_kernel, dim3(512), dim3(512), 0, stream, wht, ei, ej, bias,
                       (const unsigned*)mask, out);
}

// Round 9
// 241.479 us; speedup vs baseline: 1.2212x; 1.0161x over previous
//
#include <hip/hip_runtime.h>
#include <string.h>

#define ALPHA 0.2f
// B=128, L=512, FIN=FOUT=128. Global I/O fp32; internal GEMMs bf16 MFMA.

typedef short short8 __attribute__((ext_vector_type(8)));
typedef float floatx4 __attribute__((ext_vector_type(4)));
typedef unsigned short ushort4v __attribute__((ext_vector_type(4)));

__device__ inline unsigned short f2bf(float f) {
    unsigned int v; __builtin_memcpy(&v, &f, 4);
    v = v + 0x7FFFu + ((v >> 16) & 1u);   // RNE
    return (unsigned short)(v >> 16);
}

// Inline-asm nontemporal 16B load: volatile program order = pipeline the
// compiler cannot collapse. Completion is enforced ONLY by our counted
// s_waitcnt vmcnt(N) + sched_barrier(0) (rule: compiler doesn't track these).
#define GLD4(dst, p) asm volatile("global_load_dwordx4 %0, %1, off nt" : "=v"(dst) : "v"(p))

// ---------------------------------------------------------------------------
// Kernel 1 (R8 v2): only W staged in LDS (35KB -> 4 blk/CU); h global->reg;
// mask pack folded in (blocks 0..127). grid 512 x 256.
// ---------------------------------------------------------------------------
__global__ __launch_bounds__(256, 4) void wh_kernel(const float* __restrict__ h,
                                                    const float* __restrict__ W,
                                                    const float* __restrict__ a,
                                                    const int* __restrict__ adj,
                                                    unsigned short* __restrict__ wht,
                                                    float* __restrict__ ei,
                                                    float* __restrict__ ej,
                                                    unsigned long long* __restrict__ mask)
{
    __shared__ __align__(16) unsigned short w_s[128][136];  // [o][f] bf16
    __shared__ float a_s[256];
    const int tid  = threadIdx.x;
    const int lane = tid & 63;
    const int wv   = tid >> 6;
    const int quad = lane >> 4;
    const int l16  = lane & 15;
    const int r0   = blockIdx.x * 128;
    const int b    = r0 >> 9;
    const int jb   = r0 & 511;

    for (int it = 0; it < 64; ++it) {
        int idx = it * 256 + tid;
        w_s[idx & 127][idx >> 7] = f2bf(W[idx]);
    }
    a_s[tid] = a[tid];

    if (blockIdx.x < 128) {
        const int row = blockIdx.x * 4 + wv;
        const int* ar = adj + row * 512;
        unsigned long long wbits[8];
#pragma unroll
        for (int q = 0; q < 8; ++q) wbits[q] = __ballot(ar[q * 64 + lane] != 0);
        if (lane == 0) {
            unsigned long long* mr = mask + row * 8;
#pragma unroll
            for (int q = 0; q < 8; ++q) mr[q] = wbits[q];
        }
    }
    __syncthreads();

    const float* hp0 = h + (size_t)(r0 + wv * 32 + l16) * 128 + quad * 8;
    const float* hp1 = hp0 + 16 * 128;

    floatx4 acc[8][2];
    for (int mo = 0; mo < 8; ++mo)
        for (int n = 0; n < 2; ++n) acc[mo][n] = (floatx4)0.f;

    floatx4 c00 = *(const floatx4*)(hp0);
    floatx4 c01 = *(const floatx4*)(hp0 + 4);
    floatx4 c10 = *(const floatx4*)(hp1);
    floatx4 c11 = *(const floatx4*)(hp1 + 4);
#pragma unroll
    for (int kk = 0; kk < 4; ++kk) {
        floatx4 n00, n01, n10, n11;
        if (kk < 3) {
            n00 = *(const floatx4*)(hp0 + (kk + 1) * 32);
            n01 = *(const floatx4*)(hp0 + (kk + 1) * 32 + 4);
            n10 = *(const floatx4*)(hp1 + (kk + 1) * 32);
            n11 = *(const floatx4*)(hp1 + (kk + 1) * 32 + 4);
        }
        short8 bfr0, bfr1;
#pragma unroll
        for (int e = 0; e < 4; ++e) {
            bfr0[e]     = (short)f2bf(c00[e]);
            bfr0[4 + e] = (short)f2bf(c01[e]);
            bfr1[e]     = (short)f2bf(c10[e]);
            bfr1[4 + e] = (short)f2bf(c11[e]);
        }
#pragma unroll
        for (int mo = 0; mo < 8; ++mo) {
            short8 afr = *(const short8*)&w_s[mo * 16 + l16][kk * 32 + quad * 8];
            acc[mo][0] = __builtin_amdgcn_mfma_f32_16x16x32_bf16(afr, bfr0, acc[mo][0], 0, 0, 0);
            acc[mo][1] = __builtin_amdgcn_mfma_f32_16x16x32_bf16(afr, bfr1, acc[mo][1], 0, 0, 0);
        }
        c00 = n00; c01 = n01; c10 = n10; c11 = n11;
    }

    for (int n = 0; n < 2; ++n) {
        float si = 0.f, sj = 0.f;
        for (int mo = 0; mo < 8; ++mo)
            for (int r = 0; r < 4; ++r) {
                int o = mo * 16 + quad * 4 + r;
                float v = acc[mo][n][r];
                si += v * a_s[o];
                sj += v * a_s[128 + o];
            }
        si += __shfl_xor(si, 16); si += __shfl_xor(si, 32);
        sj += __shfl_xor(sj, 16); sj += __shfl_xor(sj, 32);
        if (quad == 0) {
            int j = jb + wv * 32 + n * 16 + l16;
            ei[b * 512 + j] = si;
            ej[b * 512 + j] = sj;
        }
    }

    for (int mo = 0; mo < 8; ++mo)
        for (int n = 0; n < 2; ++n)
            for (int r = 0; r < 4; ++r) {
                int o = mo * 16 + quad * 4 + r;
                int j = jb + wv * 32 + n * 16 + l16;
                wht[(size_t)b * 65536 + o * 512 + j] = f2bf(acc[mo][n][r]);
            }
}

// ---------------------------------------------------------------------------
// Kernel 2 (R6 shell + asm-pipelined Phase A): 64-row i-tiles, 512 threads,
// XCD remap. Phase A: depth-4 asm global_load stream with counted vmcnt
// (6,6,6,6,6,4,2,0) — never drains mid-loop. ej/ei/mask staged to LDS first
// so Phase A contains NO compiler-tracked VMEM (vmcnt counting stays exact).
// LDS ~72KB -> 2 blk/CU = 16 waves/CU. grid 1024 x 512.
// ---------------------------------------------------------------------------
__global__ __launch_bounds__(512, 4) void attn_kernel(const unsigned short* __restrict__ wht,
                                                      const float* __restrict__ ei,
                                                      const float* __restrict__ ej,
                                                      const float* __restrict__ bias,
                                                      const unsigned* __restrict__ mask32,
                                                      float* __restrict__ out)
{
    __shared__ __align__(16) unsigned short p_s[64][520];
    __shared__ float ei_s[64];
    __shared__ float ej_s[512];
    __shared__ float s_row[64];
    __shared__ unsigned m_s[64][16];

    const int tid  = threadIdx.x;
    const int lane = tid & 63;
    const int wv   = tid >> 6;        // 0..7
    const int quad = lane >> 4;
    const int l16  = lane & 15;

    // XCD-aware decode (R6): x = bid&7 is the XCD under HW round-robin.
    const int n  = blockIdx.x;
    const int x  = n & 7;
    const int r  = n >> 3;            // 0..127
    const int b  = x * 16 + (r >> 3);
    const int i0 = (r & 7) * 64;

    // Stage everything Phase A needs into LDS (vmcnt-clean afterwards).
    ej_s[tid] = ej[b * 512 + tid];
    if (tid < 64) ei_s[tid] = ei[b * 512 + i0 + tid];
#pragma unroll
    for (int it = 0; it < 2; ++it) {
        int idx = it * 512 + tid;
        m_s[idx >> 4][idx & 15] = mask32[i0 * 16 + idx];
    }
    __syncthreads();

    const float* bp = bias + ((size_t)(b * 512 + i0 + wv * 8)) * 512;
    const int mw = lane >> 3;
    const int ms = (lane & 7) * 4;

    const floatx4 ejv0 = *(const floatx4*)&ej_s[lane * 4];
    const floatx4 ejv1 = *(const floatx4*)&ej_s[256 + lane * 4];

    // ---- Phase A: depth-4 asm pipeline (rows 0..3 in flight) ----
    floatx4 q0[4], q1[4];
    GLD4(q0[0], bp + lane * 4);            GLD4(q1[0], bp + 256 + lane * 4);
    GLD4(q0[1], bp + 512 + lane * 4);      GLD4(q1[1], bp + 768 + lane * 4);
    GLD4(q0[2], bp + 1024 + lane * 4);     GLD4(q1[2], bp + 1280 + lane * 4);
    GLD4(q0[3], bp + 1536 + lane * 4);     GLD4(q1[3], bp + 1792 + lane * 4);

    float rsum[8];
#pragma unroll
    for (int rr = 0; rr < 8; ++rr) {
        if (rr <= 4)      asm volatile("s_waitcnt vmcnt(6)" ::: "memory");
        else if (rr == 5) asm volatile("s_waitcnt vmcnt(4)" ::: "memory");
        else if (rr == 6) asm volatile("s_waitcnt vmcnt(2)" ::: "memory");
        else              asm volatile("s_waitcnt vmcnt(0)" ::: "memory");
        __builtin_amdgcn_sched_barrier(0);

        const int s  = rr & 3;
        const int il = wv * 8 + rr;
        const float eiv = ei_s[il];
        const unsigned nib0 = (m_s[il][mw]     >> ms) & 0xFu;
        const unsigned nib1 = (m_s[il][8 + mw] >> ms) & 0xFu;
        float sm = 0.f;
        ushort4v p0, p1;
#pragma unroll
        for (int e = 0; e < 4; ++e) {
            float xv = eiv + ejv0[e];
            xv = fmaxf(xv, ALPHA * xv);            // leaky relu
            xv += q0[s][e];
            float p = __expf(xv);                  // no max-subtraction (|x| small)
            p = (nib0 & (1u << e)) ? p : 0.f;
            sm += p;
            p0[e] = f2bf(p);
        }
#pragma unroll
        for (int e = 0; e < 4; ++e) {
            float xv = eiv + ejv1[e];
            xv = fmaxf(xv, ALPHA * xv);
            xv += q1[s][e];
            float p = __expf(xv);
            p = (nib1 & (1u << e)) ? p : 0.f;
            sm += p;
            p1[e] = f2bf(p);
        }
        *(ushort4v*)&p_s[il][lane * 4]       = p0;
        *(ushort4v*)&p_s[il][256 + lane * 4] = p1;
        rsum[rr] = sm;

        if (rr < 4) {                              // refill slot s with row rr+4
            GLD4(q0[s], bp + (size_t)(rr + 4) * 512 + lane * 4);
            GLD4(q1[s], bp + (size_t)(rr + 4) * 512 + 256 + lane * 4);
        }
    }

    // Deferred row-sum reductions
#pragma unroll
    for (int rr = 0; rr < 8; ++rr)
        for (int off = 32; off; off >>= 1)
            rsum[rr] += __shfl_xor(rsum[rr], off);
    if (lane == 0)
#pragma unroll
        for (int rr = 0; rr < 8; ++rr) s_row[wv * 8 + rr] = rsum[rr];
    __syncthreads();

    // ---- Phase B (R6): C[64x16] per wave = P[64x512] @ Wh[512x16-slice] ----
    floatx4 acc[4];
#pragma unroll
    for (int m = 0; m < 4; ++m) acc[m] = (floatx4)0.f;

    const unsigned short* wb = wht + (size_t)b * 65536 + (wv * 16 + l16) * 512 + quad * 8;
    short8 bf = *(const short8*)(wb);
#pragma unroll
    for (int k16 = 0; k16 < 16; ++k16) {
        int ko = k16 * 32 + quad * 8;
        short8 nbf;
        if (k16 < 15) nbf = *(const short8*)(wb + (k16 + 1) * 32);
        short8 af0 = *(const short8*)&p_s[l16][ko];
        short8 af1 = *(const short8*)&p_s[16 + l16][ko];
        short8 af2 = *(const short8*)&p_s[32 + l16][ko];
        short8 af3 = *(const short8*)&p_s[48 + l16][ko];
        acc[0] = __builtin_amdgcn_mfma_f32_16x16x32_bf16(af0, bf, acc[0], 0, 0, 0);
        acc[1] = __builtin_amdgcn_mfma_f32_16x16x32_bf16(af1, bf, acc[1], 0, 0, 0);
        acc[2] = __builtin_amdgcn_mfma_f32_16x16x32_bf16(af2, bf, acc[2], 0, 0, 0);
        acc[3] = __builtin_amdgcn_mfma_f32_16x16x32_bf16(af3, bf, acc[3], 0, 0, 0);
        bf = nbf;
    }

    // ---- Epilogue: normalize, elu, fp32 nontemporal store ----
#pragma unroll
    for (int m = 0; m < 4; ++m)
#pragma unroll
        for (int rr2 = 0; rr2 < 4; ++rr2) {
            int il = m * 16 + quad * 4 + rr2;
            int o  = wv * 16 + l16;
            float v = acc[m][rr2] / s_row[il];
            v = v > 0.f ? v : (__expf(v) - 1.f);
            __builtin_nontemporal_store(v, &out[((size_t)(b * 512 + i0 + il)) * 128 + o]);
        }
}

// ---------------------------------------------------------------------------
extern "C" void kernel_launch(void* const* d_in, const int* in_sizes, int n_in,
                              void* d_out, int out_size, void* d_ws, size_t ws_size,
                              hipStream_t stream)
{
    const float* h    = (const float*)d_in[0];
    const float* W    = (const float*)d_in[1];
    const float* a    = (const float*)d_in[2];
    const float* bias = (const float*)d_in[3];
    const int*   adj  = (const int*)d_in[4];
    float*       out  = (float*)d_out;

    unsigned short* wht = (unsigned short*)d_ws;          // 16.78 MB bf16 Wh_t[b][o][j]
    float* ei = (float*)((char*)d_ws + 16777216);         // 256 KB
    float* ej = ei + 65536;                               // 256 KB
    unsigned long long* mask = (unsigned long long*)((char*)d_ws + 17301504); // 32 KB

    hipLaunchKernelGGL(wh_kernel,   dim3(512),  dim3(256), 0, stream, h, W, a, adj, wht, ei, ej, mask);
    hipLaunchKernelGGL(attn_kernel, dim3(1024), dim3(512), 0, stream, wht, ei, ej, bias,
                       (const unsigned*)mask, out);
}

// Round 10
// 238.514 us; speedup vs baseline: 1.2364x; 1.0124x over previous
//
#include <hip/hip_runtime.h>
#include <string.h>

#define ALPHA 0.2f
// B=128, L=512, FIN=FOUT=128. Global I/O fp32; internal GEMMs bf16 MFMA.

typedef short short8 __attribute__((ext_vector_type(8)));
typedef float floatx4 __attribute__((ext_vector_type(4)));
typedef unsigned short ushort4v __attribute__((ext_vector_type(4)));

__device__ inline unsigned short f2bf(float f) {
    unsigned int v; __builtin_memcpy(&v, &f, 4);
    v = v + 0x7FFFu + ((v >> 16) & 1u);   // RNE
    return (unsigned short)(v >> 16);
}

// Inline-asm nontemporal 16B load: volatile program order = pipeline the
// compiler cannot collapse; completion enforced only by counted vmcnt.
#define GLD4(dst, p) asm volatile("global_load_dwordx4 %0, %1, off nt" : "=v"(dst) : "v"(p))

// ---------------------------------------------------------------------------
// Kernel 1 (R8/R9 proven): only W staged in LDS; h global->reg; mask pack
// folded in (blocks 0..127). grid 512 x 256.
// ---------------------------------------------------------------------------
__global__ __launch_bounds__(256, 4) void wh_kernel(const float* __restrict__ h,
                                                    const float* __restrict__ W,
                                                    const float* __restrict__ a,
                                                    const int* __restrict__ adj,
                                                    unsigned short* __restrict__ wht,
                                                    float* __restrict__ ei,
                                                    float* __restrict__ ej,
                                                    unsigned long long* __restrict__ mask)
{
    __shared__ __align__(16) unsigned short w_s[128][136];  // [o][f] bf16
    __shared__ float a_s[256];
    const int tid  = threadIdx.x;
    const int lane = tid & 63;
    const int wv   = tid >> 6;
    const int quad = lane >> 4;
    const int l16  = lane & 15;
    const int r0   = blockIdx.x * 128;
    const int b    = r0 >> 9;
    const int jb   = r0 & 511;

    for (int it = 0; it < 64; ++it) {
        int idx = it * 256 + tid;
        w_s[idx & 127][idx >> 7] = f2bf(W[idx]);
    }
    a_s[tid] = a[tid];

    if (blockIdx.x < 128) {
        const int row = blockIdx.x * 4 + wv;
        const int* ar = adj + row * 512;
        unsigned long long wbits[8];
#pragma unroll
        for (int q = 0; q < 8; ++q) wbits[q] = __ballot(ar[q * 64 + lane] != 0);
        if (lane == 0) {
            unsigned long long* mr = mask + row * 8;
#pragma unroll
            for (int q = 0; q < 8; ++q) mr[q] = wbits[q];
        }
    }
    __syncthreads();

    const float* hp0 = h + (size_t)(r0 + wv * 32 + l16) * 128 + quad * 8;
    const float* hp1 = hp0 + 16 * 128;

    floatx4 acc[8][2];
    for (int mo = 0; mo < 8; ++mo)
        for (int n = 0; n < 2; ++n) acc[mo][n] = (floatx4)0.f;

    floatx4 c00 = *(const floatx4*)(hp0);
    floatx4 c01 = *(const floatx4*)(hp0 + 4);
    floatx4 c10 = *(const floatx4*)(hp1);
    floatx4 c11 = *(const floatx4*)(hp1 + 4);
#pragma unroll
    for (int kk = 0; kk < 4; ++kk) {
        floatx4 n00, n01, n10, n11;
        if (kk < 3) {
            n00 = *(const floatx4*)(hp0 + (kk + 1) * 32);
            n01 = *(const floatx4*)(hp0 + (kk + 1) * 32 + 4);
            n10 = *(const floatx4*)(hp1 + (kk + 1) * 32);
            n11 = *(const floatx4*)(hp1 + (kk + 1) * 32 + 4);
        }
        short8 bfr0, bfr1;
#pragma unroll
        for (int e = 0; e < 4; ++e) {
            bfr0[e]     = (short)f2bf(c00[e]);
            bfr0[4 + e] = (short)f2bf(c01[e]);
            bfr1[e]     = (short)f2bf(c10[e]);
            bfr1[4 + e] = (short)f2bf(c11[e]);
        }
#pragma unroll
        for (int mo = 0; mo < 8; ++mo) {
            short8 afr = *(const short8*)&w_s[mo * 16 + l16][kk * 32 + quad * 8];
            acc[mo][0] = __builtin_amdgcn_mfma_f32_16x16x32_bf16(afr, bfr0, acc[mo][0], 0, 0, 0);
            acc[mo][1] = __builtin_amdgcn_mfma_f32_16x16x32_bf16(afr, bfr1, acc[mo][1], 0, 0, 0);
        }
        c00 = n00; c01 = n01; c10 = n10; c11 = n11;
    }

    for (int n = 0; n < 2; ++n) {
        float si = 0.f, sj = 0.f;
        for (int mo = 0; mo < 8; ++mo)
            for (int r = 0; r < 4; ++r) {
                int o = mo * 16 + quad * 4 + r;
                float v = acc[mo][n][r];
                si += v * a_s[o];
                sj += v * a_s[128 + o];
            }
        si += __shfl_xor(si, 16); si += __shfl_xor(si, 32);
        sj += __shfl_xor(sj, 16); sj += __shfl_xor(sj, 32);
        if (quad == 0) {
            int j = jb + wv * 32 + n * 16 + l16;
            ei[b * 512 + j] = si;
            ej[b * 512 + j] = sj;
        }
    }

    for (int mo = 0; mo < 8; ++mo)
        for (int n = 0; n < 2; ++n)
            for (int r = 0; r < 4; ++r) {
                int o = mo * 16 + quad * 4 + r;
                int j = jb + wv * 32 + n * 16 + l16;
                wht[(size_t)b * 65536 + o * 512 + j] = f2bf(acc[mo][n][r]);
            }
}

// ---------------------------------------------------------------------------
// Kernel 2: wave-specialized producer-consumer. Grid 256 (1 blk/CU, XCD remap,
// no tail). Block = (b, 256-row half). Waves 0-3 stream bias (asm depth-4,
// vmcnt(6) steady, prefetch ACROSS raw s_barriers - vmcnt never drained) and
// produce P chunks (16 rows) + row sums into a 2-buffer LDS ring. Waves 4-7
// consume: chunk GEMM vs L2-resident wht + normalize/elu/nt-store. Consumer
// work (~700cy) hides under producer BW time (~3200cy) -> HBM stream never
// pauses. 17 stages. LDS ~51.6KB.
// ---------------------------------------------------------------------------
__global__ __launch_bounds__(512, 2) void attn_kernel(const unsigned short* __restrict__ wht,
                                                      const float* __restrict__ ei,
                                                      const float* __restrict__ ej,
                                                      const float* __restrict__ bias,
                                                      const unsigned* __restrict__ mask32,
                                                      float* __restrict__ out)
{
    __shared__ __align__(16) unsigned short p_s[2][16][520];
    __shared__ float ei_s[256];
    __shared__ float ej_s[512];
    __shared__ float s_row[2][16];
    __shared__ unsigned m_s[256][16];

    const int tid  = threadIdx.x;
    const int lane = tid & 63;
    const int wv   = tid >> 6;        // 0..7
    const int quad = lane >> 4;
    const int l16  = lane & 15;

    // XCD-aware decode: x = bid&7 is the XCD under HW round-robin.
    const int x     = blockIdx.x & 7;
    const int r     = blockIdx.x >> 3;    // 0..31
    const int b     = x * 16 + (r >> 1);  // each XCD owns 16 consecutive b's
    const int hrow0 = (r & 1) * 256;      // half of the i-range

    // Stage ej (all 512 j), ei + mask for our 256 rows. __syncthreads drains
    // all VMEM -> producer vmcnt counting starts from 0.
    if (tid < 128) *(floatx4*)&ej_s[tid * 4] = *(const floatx4*)(ej + b * 512 + tid * 4);
    else if (tid < 384) ei_s[tid - 128] = ei[b * 512 + hrow0 + (tid - 128)];
#pragma unroll
    for (int it = 0; it < 8; ++it) {
        int idx = it * 512 + tid;
        ((unsigned*)m_s)[idx] = mask32[hrow0 * 16 + idx];
    }
    __syncthreads();

    const int mw = lane >> 3;
    const int ms = (lane & 7) * 4;

    if (wv < 4) {
        // ============================ PRODUCER ============================
        const floatx4 ejv0 = *(const floatx4*)&ej_s[lane * 4];
        const floatx4 ejv1 = *(const floatx4*)&ej_s[256 + lane * 4];
        const int w = wv;
        const float* bp = bias + ((size_t)(b * 512 + hrow0 + w * 4)) * 512;

        floatx4 q0[4], q1[4];
#pragma unroll
        for (int rr = 0; rr < 4; ++rr) {          // prime chunk 0 (8 loads)
            GLD4(q0[rr], bp + rr * 512 + lane * 4);
            GLD4(q1[rr], bp + rr * 512 + 256 + lane * 4);
        }

        for (int c = 0; c < 16; ++c) {
            const int pb = c & 1;
            const bool last = (c == 15);
            float rs[4];
#pragma unroll
            for (int rr = 0; rr < 4; ++rr) {
                // steady state: 8 outstanding (4 this-chunk rows + refills)
                if (!last || rr == 0) asm volatile("s_waitcnt vmcnt(6)" ::: "memory");
                else if (rr == 1)     asm volatile("s_waitcnt vmcnt(4)" ::: "memory");
                else if (rr == 2)     asm volatile("s_waitcnt vmcnt(2)" ::: "memory");
                else                  asm volatile("s_waitcnt vmcnt(0)" ::: "memory");
                __builtin_amdgcn_sched_barrier(0);

                const int il   = w * 4 + rr;          // row within chunk
                const int lrow = c * 16 + il;         // row within half
                const float eiv = ei_s[lrow];
                const unsigned nib0 = (m_s[lrow][mw]     >> ms) & 0xFu;
                const unsigned nib1 = (m_s[lrow][8 + mw] >> ms) & 0xFu;
                float sm = 0.f;
                ushort4v o0, o1;
#pragma unroll
                for (int e = 0; e < 4; ++e) {
                    float xv = eiv + ejv0[e];
                    xv = fmaxf(xv, ALPHA * xv);        // leaky relu
                    xv += q0[rr][e];
                    float p = __expf(xv);              // no max-sub (|x| small)
                    p = (nib0 & (1u << e)) ? p : 0.f;
                    sm += p;
                    o0[e] = f2bf(p);
                }
#pragma unroll
                for (int e = 0; e < 4; ++e) {
                    float xv = eiv + ejv1[e];
                    xv = fmaxf(xv, ALPHA * xv);
                    xv += q1[rr][e];
                    float p = __expf(xv);
                    p = (nib1 & (1u << e)) ? p : 0.f;
                    sm += p;
                    o1[e] = f2bf(p);
                }
                *(ushort4v*)&p_s[pb][il][lane * 4]       = o0;
                *(ushort4v*)&p_s[pb][il][256 + lane * 4] = o1;
                rs[rr] = sm;
                if (!last) {                           // refill: next chunk's row rr
                    GLD4(q0[rr], bp + (16 + rr) * 512 + lane * 4);
                    GLD4(q1[rr], bp + (16 + rr) * 512 + 256 + lane * 4);
                }
            }
#pragma unroll
            for (int rr = 0; rr < 4; ++rr) {
                float v = rs[rr];
                for (int off = 32; off; off >>= 1) v += __shfl_xor(v, off);
                if (lane == 0) s_row[pb][w * 4 + rr] = v;
            }
            bp += 16 * 512;
            asm volatile("s_waitcnt lgkmcnt(0)" ::: "memory");  // drain ds_writes
            __builtin_amdgcn_s_barrier();                       // NO vmcnt drain
            asm volatile("" ::: "memory");
        }
        // final stage: consumers eat chunk 15
        asm volatile("s_waitcnt lgkmcnt(0)" ::: "memory");
        __builtin_amdgcn_s_barrier();
        asm volatile("" ::: "memory");
    } else {
        // ============================ CONSUMER ============================
        const int w2 = wv - 4;                        // 0..3, o-slice of 32
        const unsigned short* wb0 = wht + (size_t)b * 65536 + (w2 * 32 + l16) * 512 + quad * 8;
        const unsigned short* wb1 = wb0 + 16 * 512;

        // idle during chunk-0 production
        asm volatile("s_waitcnt lgkmcnt(0)" ::: "memory");
        __builtin_amdgcn_s_barrier();
        asm volatile("" ::: "memory");

        for (int c = 0; c < 16; ++c) {
            const int pb = c & 1;
            floatx4 acc0 = (floatx4)0.f, acc1 = (floatx4)0.f;
            short8 bf0 = *(const short8*)(wb0);       // L2/L1-hot after chunk 0
            short8 bf1 = *(const short8*)(wb1);
#pragma unroll
            for (int k16 = 0; k16 < 16; ++k16) {
                int ko = k16 * 32 + quad * 8;
                short8 nbf0, nbf1;
                if (k16 < 15) {
                    nbf0 = *(const short8*)(wb0 + (k16 + 1) * 32);
                    nbf1 = *(const short8*)(wb1 + (k16 + 1) * 32);
                }
                short8 af = *(const short8*)&p_s[pb][l16][ko];
                acc0 = __builtin_amdgcn_mfma_f32_16x16x32_bf16(af, bf0, acc0, 0, 0, 0);
                acc1 = __builtin_amdgcn_mfma_f32_16x16x32_bf16(af, bf1, acc1, 0, 0, 0);
                bf0 = nbf0; bf1 = nbf1;
            }
            // epilogue for this chunk: normalize, elu, nt store
#pragma unroll
            for (int rr = 0; rr < 4; ++rr) {
                int il = quad * 4 + rr;
                float inv = 1.0f / s_row[pb][il];
                size_t orow = ((size_t)(b * 512 + hrow0 + c * 16 + il)) * 128;
                float v0 = acc0[rr] * inv;
                v0 = v0 > 0.f ? v0 : (__expf(v0) - 1.f);
                __builtin_nontemporal_store(v0, &out[orow + w2 * 32 + l16]);
                float v1 = acc1[rr] * inv;
                v1 = v1 > 0.f ? v1 : (__expf(v1) - 1.f);
                __builtin_nontemporal_store(v1, &out[orow + w2 * 32 + 16 + l16]);
            }
            asm volatile("s_waitcnt lgkmcnt(0)" ::: "memory");
            __builtin_amdgcn_s_barrier();
            asm volatile("" ::: "memory");
        }
    }
}

// ---------------------------------------------------------------------------
extern "C" void kernel_launch(void* const* d_in, const int* in_sizes, int n_in,
                              void* d_out, int out_size, void* d_ws, size_t ws_size,
                              hipStream_t stream)
{
    const float* h    = (const float*)d_in[0];
    const float* W    = (const float*)d_in[1];
    const float* a    = (const float*)d_in[2];
    const float* bias = (const float*)d_in[3];
    const int*   adj  = (const int*)d_in[4];
    float*       out  = (float*)d_out;

    unsigned short* wht = (unsigned short*)d_ws;          // 16.78 MB bf16 Wh_t[b][o][j]
    float* ei = (float*)((char*)d_ws + 16777216);         // 256 KB
    float* ej = ei + 65536;                               // 256 KB
    unsigned long long* mask = (unsigned long long*)((char*)d_ws + 17301504); // 32 KB

    hipLaunchKernelGGL(wh_kernel,   dim3(512), dim3(256), 0, stream, h, W, a, adj, wht, ei, ej, mask);
    hipLaunchKernelGGL(attn_kernel, dim3(256), dim3(512), 0, stream, wht, ei, ej, bias,
                       (const unsigned*)mask, out);
}